// Round 1
// baseline (350.539 us; speedup 1.0000x reference)
//
#include <hip/hip_runtime.h>
#include <hip/hip_bf16.h>
#include <stdint.h>

typedef __bf16 bf16_t;
typedef __bf16 bf16x4_t __attribute__((ext_vector_type(4)));
typedef __bf16 bf16x8_t __attribute__((ext_vector_type(8)));
typedef float f32x4_t __attribute__((ext_vector_type(4)));

#define S_LEN   2048
#define DMODEL  1024
#define NH      16
#define DH      64
#define EPS_SCALED (-1.25e8f)   // -1e9 / sqrt(64), masks applied BEFORE scaling

// ---------------- fp32 -> bf16 convert (x) ----------------
__global__ void k_cvt_bf16(const float* __restrict__ in, bf16_t* __restrict__ out, int n4) {
  int i = blockIdx.x * blockDim.x + threadIdx.x;
  if (i >= n4) return;
  float4 v = reinterpret_cast<const float4*>(in)[i];
  bf16x4_t o = {(bf16_t)v.x, (bf16_t)v.y, (bf16_t)v.z, (bf16_t)v.w};
  reinterpret_cast<bf16x4_t*>(out)[i] = o;
}

// ---------------- fp32 [R][C] -> bf16 [C][R] (weight transpose) ----------------
__global__ void k_transpose_bf16(const float* __restrict__ in, bf16_t* __restrict__ out,
                                 int R, int C) {
  __shared__ float tile[32][33];
  int c0 = blockIdx.x * 32, r0 = blockIdx.y * 32;
  int tx = threadIdx.x, ty = threadIdx.y;   // block (32,8)
  for (int i = ty; i < 32; i += 8)
    tile[i][tx] = in[(size_t)(r0 + i) * C + (c0 + tx)];
  __syncthreads();
  for (int i = ty; i < 32; i += 8)
    out[(size_t)(c0 + i) * R + (r0 + tx)] = (bf16_t)tile[tx][i];
}

// ---------------- bf16 GEMM: C[M][N] = A[M][K] * Bt[N][K]^T + bias ----------------
// MODE 0: QKV epilogue -> route to Qb/Kb [b,h,s,d] and Vt [b,h,d,s] (bf16)
// MODE 1: proj epilogue -> fp32 Out[M][N]
template<int MODE>
__global__ __launch_bounds__(256)
void k_gemm(const bf16_t* __restrict__ A, const bf16_t* __restrict__ Bt,
            const float* __restrict__ bias,
            bf16_t* __restrict__ Qb, bf16_t* __restrict__ Kb, bf16_t* __restrict__ Vt,
            float* __restrict__ Out, int M, int N, int K) {
  __shared__ alignas(16) bf16_t As[128 * 64];
  __shared__ alignas(16) bf16_t Bs[128 * 64];
  const int tid = threadIdx.x;
  const int lane = tid & 63;
  const int w = tid >> 6;
  const int m0 = blockIdx.y * 128;
  const int n0 = blockIdx.x * 128;
  const int wm = (w >> 1) * 64, wn = (w & 1) * 64;
  const int l15 = lane & 15, lg = lane >> 4;
  const int srow = tid >> 3;          // 0..31
  const int scol = (tid & 7) * 8;     // 0..56 (elems)

  f32x4_t acc[4][4] = {};

  for (int k0 = 0; k0 < K; k0 += 64) {
    __syncthreads();
    for (int p = 0; p < 4; ++p) {
      int r = p * 32 + srow;
      *reinterpret_cast<bf16x8_t*>(&As[r * 64 + scol]) =
          *reinterpret_cast<const bf16x8_t*>(&A[(size_t)(m0 + r) * K + k0 + scol]);
      *reinterpret_cast<bf16x8_t*>(&Bs[r * 64 + scol]) =
          *reinterpret_cast<const bf16x8_t*>(&Bt[(size_t)(n0 + r) * K + k0 + scol]);
    }
    __syncthreads();
    for (int kk = 0; kk < 64; kk += 32) {
      bf16x8_t a[4], b[4];
      const int kof = kk + 8 * lg;
      for (int i = 0; i < 4; ++i)
        a[i] = *reinterpret_cast<const bf16x8_t*>(&As[(wm + i * 16 + l15) * 64 + kof]);
      for (int j = 0; j < 4; ++j)
        b[j] = *reinterpret_cast<const bf16x8_t*>(&Bs[(wn + j * 16 + l15) * 64 + kof]);
      for (int i = 0; i < 4; ++i)
        for (int j = 0; j < 4; ++j)
          acc[i][j] = __builtin_amdgcn_mfma_f32_16x16x32_bf16(a[i], b[j], acc[i][j], 0, 0, 0);
    }
  }

  const int rbase = lg * 4;
  for (int i = 0; i < 4; ++i)
    for (int j = 0; j < 4; ++j) {
      int ncol = n0 + wn + j * 16 + l15;
      float bs = bias[ncol];
      for (int r = 0; r < 4; ++r) {
        int m = m0 + wm + i * 16 + rbase + r;
        float v = acc[i][j][r] + bs;
        if (MODE == 1) {
          Out[(size_t)m * N + ncol] = v;
        } else {
          int b = m >> 11, s = m & 2047;          // S = 2048
          int t = ncol >> 10, nn = ncol & 1023;   // 0:Q 1:K 2:V
          int h = nn >> 6, d = nn & 63;
          size_t bh = (size_t)b * NH + h;
          if (t == 0)      Qb[(bh * S_LEN + s) * DH + d] = (bf16_t)v;
          else if (t == 1) Kb[(bh * S_LEN + s) * DH + d] = (bf16_t)v;
          else             Vt[(bh * DH + d) * S_LEN + s] = (bf16_t)v;
        }
      }
    }
}

// ---------------- per-(b,h) mean of V over all S keys (all-masked-row fallback) ------
__global__ __launch_bounds__(256)
void k_vmean(const bf16_t* __restrict__ Vt, float* __restrict__ vmean) {
  const int bh = blockIdx.x;
  const int t = threadIdx.x;
  const int d = t >> 2, q = t & 3;
  const bf16_t* vp = Vt + ((size_t)bh * DH + d) * S_LEN + q * 512;
  float s = 0.f;
  for (int i = 0; i < 512; i += 8) {
    bf16x8_t v = *reinterpret_cast<const bf16x8_t*>(&vp[i]);
    for (int j = 0; j < 8; ++j) s += (float)v[j];
  }
  __shared__ float part[256];
  part[t] = s;
  __syncthreads();
  if (q == 0)
    vmean[bh * DH + d] = (part[t] + part[t + 1] + part[t + 2] + part[t + 3]) * (1.f / 2048.f);
}

// ---------------- flash attention: one wave = 16 query rows ----------------
__global__ __launch_bounds__(256)
void k_attn(const bf16_t* __restrict__ Qb, const bf16_t* __restrict__ Kb,
            const bf16_t* __restrict__ Vt, const int* __restrict__ amask,
            const float* __restrict__ vmean, bf16_t* __restrict__ ctxb) {
  __shared__ alignas(16) bf16_t Plds[4][16 * 40];   // per-wave P bounce, stride 40 elems
  const int tid = threadIdx.x, lane = tid & 63, w = tid >> 6;
  const int bh = blockIdx.y, b = bh >> 4, h = bh & 15;
  const int qbase = blockIdx.x * 64 + w * 16;
  const bf16_t* Qp = Qb + (size_t)bh * S_LEN * DH;
  const bf16_t* Kp = Kb + (size_t)bh * S_LEN * DH;
  const bf16_t* Vp = Vt + (size_t)bh * DH * S_LEN;
  const int* mp = amask + b * S_LEN;
  const int l15 = lane & 15, lg = lane >> 4;

  // Q fragments stay in registers for the whole kernel
  bf16x8_t qf0 = *reinterpret_cast<const bf16x8_t*>(&Qp[(qbase + l15) * DH + 8 * lg]);
  bf16x8_t qf1 = *reinterpret_cast<const bf16x8_t*>(&Qp[(qbase + l15) * DH + 32 + 8 * lg]);

  f32x4_t po[4] = {};
  float mrow[4] = {EPS_SCALED, EPS_SCALED, EPS_SCALED, EPS_SCALED};
  float lrow[4] = {0.f, 0.f, 0.f, 0.f};

  const int kend = qbase + 16;                 // causal: keys <= qbase+15
  for (int kb = 0; kb < kend; kb += 32) {
    f32x4_t s0 = {}, s1 = {};
    bf16x8_t kf;
    kf = *reinterpret_cast<const bf16x8_t*>(&Kp[(kb + l15) * DH + 8 * lg]);
    s0 = __builtin_amdgcn_mfma_f32_16x16x32_bf16(qf0, kf, s0, 0, 0, 0);
    kf = *reinterpret_cast<const bf16x8_t*>(&Kp[(kb + l15) * DH + 32 + 8 * lg]);
    s0 = __builtin_amdgcn_mfma_f32_16x16x32_bf16(qf1, kf, s0, 0, 0, 0);
    kf = *reinterpret_cast<const bf16x8_t*>(&Kp[(kb + 16 + l15) * DH + 8 * lg]);
    s1 = __builtin_amdgcn_mfma_f32_16x16x32_bf16(qf0, kf, s1, 0, 0, 0);
    kf = *reinterpret_cast<const bf16x8_t*>(&Kp[(kb + 16 + l15) * DH + 32 + 8 * lg]);
    s1 = __builtin_amdgcn_mfma_f32_16x16x32_bf16(qf1, kf, s1, 0, 0, 0);

    // mask (pad + causal, value = EPS/8) then scale by 1/sqrt(Dh)
    const int k0g = kb + l15, k1g = k0g + 16;
    const int mv0 = mp[k0g], mv1 = mp[k1g];
    float pmax[4];
    for (int r = 0; r < 4; ++r) {
      int qg = qbase + lg * 4 + r;
      float v0 = (mv0 != 0 && k0g <= qg) ? s0[r] * 0.125f : EPS_SCALED;
      float v1 = (mv1 != 0 && k1g <= qg) ? s1[r] * 0.125f : EPS_SCALED;
      s0[r] = v0; s1[r] = v1;
      pmax[r] = fmaxf(v0, v1);
    }
    for (int off = 8; off > 0; off >>= 1)
      for (int r = 0; r < 4; ++r)
        pmax[r] = fmaxf(pmax[r], __shfl_xor(pmax[r], off));

    float sc[4], psum[4];
    for (int r = 0; r < 4; ++r) {
      float mnew = fmaxf(mrow[r], pmax[r]);
      sc[r] = __expf(mrow[r] - mnew);
      mrow[r] = mnew;
      float p0 = __expf(s0[r] - mnew);
      float p1 = __expf(s1[r] - mnew);
      s0[r] = p0; s1[r] = p1;
      psum[r] = p0 + p1;
    }
    for (int off = 8; off > 0; off >>= 1)
      for (int r = 0; r < 4; ++r)
        psum[r] += __shfl_xor(psum[r], off);
    for (int r = 0; r < 4; ++r) {
      lrow[r] = lrow[r] * sc[r] + psum[r];
      for (int f = 0; f < 4; ++f) po[f][r] *= sc[r];
    }

    // transpose P (D-layout) -> A-layout via per-wave LDS bounce
    for (int r = 0; r < 4; ++r) {
      Plds[w][(lg * 4 + r) * 40 + l15]      = (bf16_t)s0[r];
      Plds[w][(lg * 4 + r) * 40 + 16 + l15] = (bf16_t)s1[r];
    }
    asm volatile("s_waitcnt lgkmcnt(0)" ::: "memory");
    bf16x8_t pa = *reinterpret_cast<const bf16x8_t*>(&Plds[w][l15 * 40 + 8 * lg]);
    for (int f = 0; f < 4; ++f) {
      bf16x8_t vf = *reinterpret_cast<const bf16x8_t*>(
          &Vp[(size_t)(f * 16 + l15) * S_LEN + kb + 8 * lg]);
      po[f] = __builtin_amdgcn_mfma_f32_16x16x32_bf16(pa, vf, po[f], 0, 0, 0);
    }
  }

  // epilogue: normalize; all-masked rows (m never left EPS) -> uniform mean of V
  for (int r = 0; r < 4; ++r) {
    int qg = qbase + lg * 4 + r;
    bf16_t* orow = ctxb + (size_t)(b * S_LEN + qg) * DMODEL + h * DH;
    if (mrow[r] < -1.0e7f) {
      for (int f = 0; f < 4; ++f)
        orow[f * 16 + l15] = (bf16_t)vmean[bh * DH + f * 16 + l15];
    } else {
      float inv = 1.0f / lrow[r];
      for (int f = 0; f < 4; ++f)
        orow[f * 16 + l15] = (bf16_t)(po[f][r] * inv);
    }
  }
}

extern "C" void kernel_launch(void* const* d_in, const int* in_sizes, int n_in,
                              void* d_out, int out_size, void* d_ws, size_t ws_size,
                              hipStream_t stream) {
  const float* x     = (const float*)d_in[0];
  const int*   amask = (const int*)d_in[1];
  const float* Wqkv  = (const float*)d_in[2];
  const float* bqkv  = (const float*)d_in[3];
  const float* Wproj = (const float*)d_in[4];
  const float* bproj = (const float*)d_in[5];
  float* out = (float*)d_out;

  char* ws = (char*)d_ws;
  bf16_t* xb    = (bf16_t*)(ws);                      // 8 MB  [4096][1024]
  bf16_t* WqT   = (bf16_t*)(ws + (8llu  << 20));      // 6 MB  [3072][1024]
  bf16_t* WpT   = (bf16_t*)(ws + (14llu << 20));      // 2 MB  [1024][1024]
  bf16_t* Qb    = (bf16_t*)(ws + (16llu << 20));      // 8 MB  [b,h,s,d]
  bf16_t* Kb    = (bf16_t*)(ws + (24llu << 20));      // 8 MB  [b,h,s,d]
  bf16_t* Vt    = (bf16_t*)(ws + (32llu << 20));      // 8 MB  [b,h,d,s]
  bf16_t* ctxb  = (bf16_t*)(ws + (40llu << 20));      // 8 MB  [4096][1024]
  float*  vmean = (float*) (ws + (48llu << 20));      // 8 KB  [32][64]

  k_cvt_bf16<<<4096, 256, 0, stream>>>(x, xb, (2 * S_LEN * DMODEL) / 4);
  k_transpose_bf16<<<dim3(3072 / 32, 1024 / 32), dim3(32, 8), 0, stream>>>(Wqkv, WqT, 1024, 3072);
  k_transpose_bf16<<<dim3(1024 / 32, 1024 / 32), dim3(32, 8), 0, stream>>>(Wproj, WpT, 1024, 1024);
  k_gemm<0><<<dim3(3072 / 128, 4096 / 128), 256, 0, stream>>>(
      xb, WqT, bqkv, Qb, Kb, Vt, nullptr, 4096, 3072, 1024);
  k_vmean<<<32, 256, 0, stream>>>(Vt, vmean);
  k_attn<<<dim3(S_LEN / 64, 32), 256, 0, stream>>>(Qb, Kb, Vt, amask, vmean, ctxb);
  k_gemm<1><<<dim3(1024 / 128, 4096 / 128), 256, 0, stream>>>(
      ctxb, WpT, bproj, nullptr, nullptr, nullptr, out, 4096, 1024, 1024);
}

// Round 2
// 304.128 us; speedup vs baseline: 1.1526x; 1.1526x over previous
//
#include <hip/hip_runtime.h>
#include <hip/hip_bf16.h>
#include <stdint.h>

typedef __bf16 bf16_t;
typedef __bf16 bf16x4_t __attribute__((ext_vector_type(4)));
typedef __bf16 bf16x8_t __attribute__((ext_vector_type(8)));
typedef float f32x4_t __attribute__((ext_vector_type(4)));

#define S_LEN   2048
#define DMODEL  1024
#define NH      16
#define DH      64
// masks applied BEFORE scaling: masked logit = -1e9/8; work in log2 domain.
#define LOG2E   1.4426950408889634f
#define SCL     (0.125f * LOG2E)            // st * SCL == (st/8)*log2(e)
#define EPS2    (-1.8033688e8f)             // (-1e9/8) * log2(e)

#define MFMA(a, b, c) __builtin_amdgcn_mfma_f32_16x16x32_bf16(a, b, c, 0, 0, 0)

#define GLOAD_LDS16(gsrc, ldst)                                         \
  __builtin_amdgcn_global_load_lds(                                     \
      (__attribute__((address_space(1))) void*)(void*)(gsrc),           \
      (__attribute__((address_space(3))) void*)(void*)(ldst), 16, 0, 0)

// ---------------- fp32 -> bf16 convert (x) ----------------
__global__ void k_cvt_bf16(const float* __restrict__ in, bf16_t* __restrict__ out, int n4) {
  int i = blockIdx.x * blockDim.x + threadIdx.x;
  if (i >= n4) return;
  float4 v = reinterpret_cast<const float4*>(in)[i];
  bf16x4_t o = {(bf16_t)v.x, (bf16_t)v.y, (bf16_t)v.z, (bf16_t)v.w};
  reinterpret_cast<bf16x4_t*>(out)[i] = o;
}

// ---------------- pad mask -> additive log2-domain float ----------------
__global__ void k_mask(const int* __restrict__ am, float* __restrict__ mskf, int n) {
  int i = blockIdx.x * blockDim.x + threadIdx.x;
  if (i < n) mskf[i] = am[i] ? 0.f : EPS2;
}

// ---------------- fp32 [R][C] -> bf16 [C][R] (weight transpose) ----------------
__global__ void k_transpose_bf16(const float* __restrict__ in, bf16_t* __restrict__ out,
                                 int R, int C) {
  __shared__ float tile[32][33];
  int c0 = blockIdx.x * 32, r0 = blockIdx.y * 32;
  int tx = threadIdx.x, ty = threadIdx.y;   // block (32,8)
  for (int i = ty; i < 32; i += 8)
    tile[i][tx] = in[(size_t)(r0 + i) * C + (c0 + tx)];
  __syncthreads();
  for (int i = ty; i < 32; i += 8)
    out[(size_t)(c0 + i) * R + (r0 + tx)] = (bf16_t)tile[tx][i];
}

// ---------------- bf16 GEMM: C[M][N] = A[M][K] * Bt[N][K]^T + bias ----------------
// MODE 0: QKV epilogue -> route to Qb/Kb [b,h,s,d] and Vt [b,h,d,s] (bf16)
// MODE 1: proj epilogue -> fp32 Out[M][N]
template<int MODE>
__global__ __launch_bounds__(256)
void k_gemm(const bf16_t* __restrict__ A, const bf16_t* __restrict__ Bt,
            const float* __restrict__ bias,
            bf16_t* __restrict__ Qb, bf16_t* __restrict__ Kb, bf16_t* __restrict__ Vt,
            float* __restrict__ Out, int M, int N, int K) {
  __shared__ alignas(16) bf16_t As[128 * 64];
  __shared__ alignas(16) bf16_t Bs[128 * 64];
  const int tid = threadIdx.x;
  const int lane = tid & 63;
  const int w = tid >> 6;
  const int m0 = blockIdx.y * 128;
  const int n0 = blockIdx.x * 128;
  const int wm = (w >> 1) * 64, wn = (w & 1) * 64;
  const int l15 = lane & 15, lg = lane >> 4;
  const int lrow = lane >> 3;          // 0..7
  const int lcol = (lane & 7) * 8;     // elems

  f32x4_t acc[4][4] = {};

  for (int k0 = 0; k0 < K; k0 += 64) {
    __syncthreads();
#pragma unroll
    for (int p = 0; p < 4; ++p) {
      const int rb = p * 32 + w * 8;   // wave-uniform row base
      GLOAD_LDS16(&A [(size_t)(m0 + rb + lrow) * K + k0 + lcol], &As[rb * 64]);
      GLOAD_LDS16(&Bt[(size_t)(n0 + rb + lrow) * K + k0 + lcol], &Bs[rb * 64]);
    }
    __syncthreads();   // barrier drains vmcnt
#pragma unroll
    for (int kk = 0; kk < 64; kk += 32) {
      bf16x8_t a[4], b[4];
      const int kof = kk + 8 * lg;
#pragma unroll
      for (int i = 0; i < 4; ++i)
        a[i] = *reinterpret_cast<const bf16x8_t*>(&As[(wm + i * 16 + l15) * 64 + kof]);
#pragma unroll
      for (int j = 0; j < 4; ++j)
        b[j] = *reinterpret_cast<const bf16x8_t*>(&Bs[(wn + j * 16 + l15) * 64 + kof]);
#pragma unroll
      for (int i = 0; i < 4; ++i)
#pragma unroll
        for (int j = 0; j < 4; ++j)
          acc[i][j] = MFMA(a[i], b[j], acc[i][j]);
    }
  }

  const int rbase = lg * 4;
#pragma unroll
  for (int i = 0; i < 4; ++i)
#pragma unroll
    for (int j = 0; j < 4; ++j) {
      int ncol = n0 + wn + j * 16 + l15;
      float bs = bias[ncol];
#pragma unroll
      for (int r = 0; r < 4; ++r) {
        int m = m0 + wm + i * 16 + rbase + r;
        float v = acc[i][j][r] + bs;
        if (MODE == 1) {
          Out[(size_t)m * N + ncol] = v;
        } else {
          int b = m >> 11, s = m & 2047;          // S = 2048
          int t = ncol >> 10, nn = ncol & 1023;   // 0:Q 1:K 2:V
          int h = nn >> 6, d = nn & 63;
          size_t bh = (size_t)b * NH + h;
          if (t == 0)      Qb[(bh * S_LEN + s) * DH + d] = (bf16_t)v;
          else if (t == 1) Kb[(bh * S_LEN + s) * DH + d] = (bf16_t)v;
          else             Vt[(bh * DH + d) * S_LEN + s] = (bf16_t)v;
        }
      }
    }
}

// ---------------- per-(b,h) mean of V over all S keys (all-masked-row fallback) ------
__global__ __launch_bounds__(256)
void k_vmean(const bf16_t* __restrict__ Vt, float* __restrict__ vmean) {
  const int bh = blockIdx.x;
  const int t = threadIdx.x;
  const int d = t >> 2, q = t & 3;
  const bf16_t* vp = Vt + ((size_t)bh * DH + d) * S_LEN + q * 512;
  float s = 0.f;
  for (int i = 0; i < 512; i += 8) {
    bf16x8_t v = *reinterpret_cast<const bf16x8_t*>(&vp[i]);
    for (int j = 0; j < 8; ++j) s += (float)v[j];
  }
  __shared__ float part[256];
  part[t] = s;
  __syncthreads();
  if (q == 0)
    vmean[bh * DH + d] = (part[t] + part[t + 1] + part[t + 2] + part[t + 3]) * (1.f / 2048.f);
}

// ---------------- flash attention, swapped-operand form ----------------
// One wave = 16 q rows. S^T = mfma(K,Q): lane holds S[k=lg*4+r][q=l15] ->
// softmax state is lane-local in q. O^T = mfma(V,P) with an in-lane k-permutation
// applied identically to P and V fragments (MFMA sums over k; any consistent
// permutation is valid). No LDS, no barriers, 4 shuffles per 64 keys.
__global__ __launch_bounds__(256)
void k_attn(const bf16_t* __restrict__ Qb, const bf16_t* __restrict__ Kb,
            const bf16_t* __restrict__ Vt, const float* __restrict__ mskf,
            const float* __restrict__ vmean, bf16_t* __restrict__ ctxb) {
  const int tid = threadIdx.x, lane = tid & 63, w = tid >> 6;
  const int bh = blockIdx.x, b = bh >> 4, h = bh & 15;   // bh fast => XCD = bh%8, K/V L2-resident
  const int qtg = blockIdx.y;
  // balanced wave->qtile pairing: every block gets equal total causal work
  const int qtile = (w == 0) ? qtg : (w == 1) ? 127 - qtg : (w == 2) ? 32 + qtg : 95 - qtg;
  const int qbase = qtile * 16;
  const int l15 = lane & 15, lg = lane >> 4;
  const int qg = qbase + l15;
  const bf16_t* Qp = Qb + (size_t)bh * S_LEN * DH;
  const bf16_t* Kp = Kb + (size_t)bh * S_LEN * DH;
  const bf16_t* Vp = Vt + (size_t)bh * DH * S_LEN;
  const float* mp = mskf + b * S_LEN;

  const bf16x8_t qf0 = *reinterpret_cast<const bf16x8_t*>(&Qp[qg * DH + 8 * lg]);
  const bf16x8_t qf1 = *reinterpret_cast<const bf16x8_t*>(&Qp[qg * DH + 32 + 8 * lg]);

  f32x4_t po[4] = {};
  float m = -1.9e8f, l = 0.f;

  const int kend = qbase + 16;
  for (int kb = 0; kb < kend; kb += 64) {
    // ---- QK^T (swapped): st[t][r] = S[k=kb+t*16+lg*4+r][q=qg] ----
    f32x4_t st[4];
#pragma unroll
    for (int t = 0; t < 4; ++t) {
      const bf16_t* kr = &Kp[(kb + t * 16 + l15) * DH + 8 * lg];
      bf16x8_t k0 = *reinterpret_cast<const bf16x8_t*>(kr);
      bf16x8_t k1 = *reinterpret_cast<const bf16x8_t*>(kr + 32);
      f32x4_t s = {};
      s = MFMA(k0, qf0, s);
      s = MFMA(k1, qf1, s);
      st[t] = s;
    }
    // ---- mask + scale (log2 domain) ----
    const bool notfull = (kb + 63 > qbase);
    float p[4][4];
    float pmax = -3.0e38f;
#pragma unroll
    for (int t = 0; t < 4; ++t) {
      f32x4_t mk = *reinterpret_cast<const f32x4_t*>(&mp[kb + t * 16 + lg * 4]);
#pragma unroll
      for (int r = 0; r < 4; ++r) {
        int k = kb + t * 16 + lg * 4 + r;
        float v = fmaf(st[t][r], SCL, mk[r]);
        if (notfull) v = (k <= qg) ? v : EPS2;
        p[t][r] = v;
        pmax = fmaxf(pmax, v);
      }
    }
    pmax = fmaxf(pmax, __shfl_xor(pmax, 16));
    pmax = fmaxf(pmax, __shfl_xor(pmax, 32));
    // ---- online softmax update (per-lane, q = l15) ----
    float mnew = fmaxf(m, pmax);
    float sc = exp2f(m - mnew);
    m = mnew;
    float psum = 0.f;
    bf16_t pb[16];
#pragma unroll
    for (int t = 0; t < 4; ++t)
#pragma unroll
      for (int r = 0; r < 4; ++r) {
        float e = exp2f(p[t][r] - mnew);
        psum += e;
        pb[t * 4 + r] = (bf16_t)e;
      }
    psum += __shfl_xor(psum, 16);
    psum += __shfl_xor(psum, 32);
    l = l * sc + psum;
#pragma unroll
    for (int f = 0; f < 4; ++f) po[f] *= sc;
    // ---- P fragments (in-lane k-permutation) ----
    bf16x8_t pf[2];
#pragma unroll
    for (int g = 0; g < 2; ++g) {
      bf16x8_t v;
#pragma unroll
      for (int j = 0; j < 4; ++j) { v[j] = pb[(2 * g) * 4 + j]; v[4 + j] = pb[(2 * g + 1) * 4 + j]; }
      pf[g] = v;
    }
    // ---- PV (swapped): po[f] holds O[d=f*16+lg*4+r][q=l15] ----
#pragma unroll
    for (int g = 0; g < 2; ++g) {
      const int so = kb + 32 * g + lg * 4;
#pragma unroll
      for (int f = 0; f < 4; ++f) {
        const bf16_t* vr = Vp + (size_t)(f * 16 + l15) * S_LEN + so;
        bf16x4_t va = *reinterpret_cast<const bf16x4_t*>(vr);
        bf16x4_t vb = *reinterpret_cast<const bf16x4_t*>(vr + 16);
        bf16x8_t vf = {va[0], va[1], va[2], va[3], vb[0], vb[1], vb[2], vb[3]};
        po[f] = MFMA(vf, pf[g], po[f]);
      }
    }
  }

  // ---- epilogue: normalize; all-masked rows -> uniform mean of V ----
  const bool dead = (m < -1.0e7f);
  const float inv = dead ? 0.f : 1.0f / l;
  bf16_t* orow = ctxb + (size_t)(b * S_LEN + qg) * DMODEL + h * DH;
  const float* vm = vmean + bh * DH;
#pragma unroll
  for (int f = 0; f < 4; ++f) {
    bf16x4_t o;
#pragma unroll
    for (int r = 0; r < 4; ++r) {
      int d = f * 16 + lg * 4 + r;
      float v = dead ? vm[d] : po[f][r] * inv;
      o[r] = (bf16_t)v;
    }
    *reinterpret_cast<bf16x4_t*>(&orow[f * 16 + lg * 4]) = o;
  }
}

extern "C" void kernel_launch(void* const* d_in, const int* in_sizes, int n_in,
                              void* d_out, int out_size, void* d_ws, size_t ws_size,
                              hipStream_t stream) {
  const float* x     = (const float*)d_in[0];
  const int*   amask = (const int*)d_in[1];
  const float* Wqkv  = (const float*)d_in[2];
  const float* bqkv  = (const float*)d_in[3];
  const float* Wproj = (const float*)d_in[4];
  const float* bproj = (const float*)d_in[5];
  float* out = (float*)d_out;

  char* ws = (char*)d_ws;
  bf16_t* xb    = (bf16_t*)(ws);                      // 8 MB  [4096][1024]
  bf16_t* WqT   = (bf16_t*)(ws + (8llu  << 20));      // 6 MB  [3072][1024]
  bf16_t* WpT   = (bf16_t*)(ws + (14llu << 20));      // 2 MB  [1024][1024]
  bf16_t* Qb    = (bf16_t*)(ws + (16llu << 20));      // 8 MB  [b,h,s,d]
  bf16_t* Kb    = (bf16_t*)(ws + (24llu << 20));      // 8 MB  [b,h,s,d]
  bf16_t* Vt    = (bf16_t*)(ws + (32llu << 20));      // 8 MB  [b,h,d,s]
  bf16_t* ctxb  = (bf16_t*)(ws + (40llu << 20));      // 8 MB  [4096][1024]
  float*  vmean = (float*) (ws + (48llu << 20));      // 8 KB  [32][64]
  float*  mskf  = (float*) (ws + (48llu << 20) + 65536);  // 16 KB [2][2048]

  k_cvt_bf16<<<4096, 256, 0, stream>>>(x, xb, (2 * S_LEN * DMODEL) / 4);
  k_mask<<<16, 256, 0, stream>>>(amask, mskf, 2 * S_LEN);
  k_transpose_bf16<<<dim3(3072 / 32, 1024 / 32), dim3(32, 8), 0, stream>>>(Wqkv, WqT, 1024, 3072);
  k_transpose_bf16<<<dim3(1024 / 32, 1024 / 32), dim3(32, 8), 0, stream>>>(Wproj, WpT, 1024, 1024);
  k_gemm<0><<<dim3(3072 / 128, 4096 / 128), 256, 0, stream>>>(
      xb, WqT, bqkv, Qb, Kb, Vt, nullptr, 4096, 3072, 1024);
  k_vmean<<<32, 256, 0, stream>>>(Vt, vmean);
  k_attn<<<dim3(32, 32), 256, 0, stream>>>(Qb, Kb, Vt, mskf, vmean, ctxb);
  k_gemm<1><<<dim3(1024 / 128, 4096 / 128), 256, 0, stream>>>(
      ctxb, WpT, bproj, nullptr, nullptr, nullptr, out, 4096, 1024, 1024);
}

// Round 3
// 230.358 us; speedup vs baseline: 1.5217x; 1.3202x over previous
//
#include <hip/hip_runtime.h>
#include <hip/hip_bf16.h>
#include <stdint.h>

typedef __bf16 bf16_t;
typedef __bf16 bf16x4_t __attribute__((ext_vector_type(4)));
typedef __bf16 bf16x8_t __attribute__((ext_vector_type(8)));
typedef float f32x4_t __attribute__((ext_vector_type(4)));

#define S_LEN   2048
#define DMODEL  1024
#define NH      16
#define DH      64
// masks applied BEFORE scaling: masked logit = -1e9/8; work in log2 domain.
#define LOG2E   1.4426950408889634f
#define SCL     (0.125f * LOG2E)            // st * SCL == (st/8)*log2(e)
#define EPS2    (-1.8033688e8f)             // (-1e9/8) * log2(e)

#define MFMA(a, b, c) __builtin_amdgcn_mfma_f32_16x16x32_bf16(a, b, c, 0, 0, 0)

#define GLOAD_LDS16(gsrc, ldst)                                         \
  __builtin_amdgcn_global_load_lds(                                     \
      (__attribute__((address_space(1))) void*)(void*)(gsrc),           \
      (__attribute__((address_space(3))) void*)(void*)(ldst), 16, 0, 0)

// ---------------- fp32 -> bf16 convert (x) ----------------
__global__ void k_cvt_bf16(const float* __restrict__ in, bf16_t* __restrict__ out, int n4) {
  int i = blockIdx.x * blockDim.x + threadIdx.x;
  if (i >= n4) return;
  float4 v = reinterpret_cast<const float4*>(in)[i];
  bf16x4_t o = {(bf16_t)v.x, (bf16_t)v.y, (bf16_t)v.z, (bf16_t)v.w};
  reinterpret_cast<bf16x4_t*>(out)[i] = o;
}

// ---------------- pad mask -> additive log2-domain float ----------------
__global__ void k_mask(const int* __restrict__ am, float* __restrict__ mskf, int n) {
  int i = blockIdx.x * blockDim.x + threadIdx.x;
  if (i < n) mskf[i] = am[i] ? 0.f : EPS2;
}

// ---------------- fp32 [R][C] -> bf16 [C][R] (weight transpose) ----------------
__global__ void k_transpose_bf16(const float* __restrict__ in, bf16_t* __restrict__ out,
                                 int R, int C) {
  __shared__ float tile[32][33];
  int c0 = blockIdx.x * 32, r0 = blockIdx.y * 32;
  int tx = threadIdx.x, ty = threadIdx.y;   // block (32,8)
  for (int i = ty; i < 32; i += 8)
    tile[i][tx] = in[(size_t)(r0 + i) * C + (c0 + tx)];
  __syncthreads();
  for (int i = ty; i < 32; i += 8)
    out[(size_t)(c0 + i) * R + (r0 + tx)] = (bf16_t)tile[tx][i];
}

// ---------------- bf16 GEMM: C[M][N] = A[M][K] * Bt[N][K]^T + bias ----------------
template<int MODE>
__global__ __launch_bounds__(256)
void k_gemm(const bf16_t* __restrict__ A, const bf16_t* __restrict__ Bt,
            const float* __restrict__ bias,
            bf16_t* __restrict__ Qb, bf16_t* __restrict__ Kb, bf16_t* __restrict__ Vt,
            float* __restrict__ Out, int M, int N, int K) {
  __shared__ alignas(16) bf16_t As[128 * 64];
  __shared__ alignas(16) bf16_t Bs[128 * 64];
  const int tid = threadIdx.x;
  const int lane = tid & 63;
  const int w = tid >> 6;
  const int m0 = blockIdx.y * 128;
  const int n0 = blockIdx.x * 128;
  const int wm = (w >> 1) * 64, wn = (w & 1) * 64;
  const int l15 = lane & 15, lg = lane >> 4;
  const int lrow = lane >> 3;          // 0..7
  const int lcol = (lane & 7) * 8;     // elems

  f32x4_t acc[4][4] = {};

  for (int k0 = 0; k0 < K; k0 += 64) {
    __syncthreads();
#pragma unroll
    for (int p = 0; p < 4; ++p) {
      const int rb = p * 32 + w * 8;   // wave-uniform row base
      GLOAD_LDS16(&A [(size_t)(m0 + rb + lrow) * K + k0 + lcol], &As[rb * 64]);
      GLOAD_LDS16(&Bt[(size_t)(n0 + rb + lrow) * K + k0 + lcol], &Bs[rb * 64]);
    }
    __syncthreads();   // barrier drains vmcnt
#pragma unroll
    for (int kk = 0; kk < 64; kk += 32) {
      bf16x8_t a[4], b[4];
      const int kof = kk + 8 * lg;
#pragma unroll
      for (int i = 0; i < 4; ++i)
        a[i] = *reinterpret_cast<const bf16x8_t*>(&As[(wm + i * 16 + l15) * 64 + kof]);
#pragma unroll
      for (int j = 0; j < 4; ++j)
        b[j] = *reinterpret_cast<const bf16x8_t*>(&Bs[(wn + j * 16 + l15) * 64 + kof]);
#pragma unroll
      for (int i = 0; i < 4; ++i)
#pragma unroll
        for (int j = 0; j < 4; ++j)
          acc[i][j] = MFMA(a[i], b[j], acc[i][j]);
    }
  }

  const int rbase = lg * 4;
#pragma unroll
  for (int i = 0; i < 4; ++i)
#pragma unroll
    for (int j = 0; j < 4; ++j) {
      int ncol = n0 + wn + j * 16 + l15;
      float bs = bias[ncol];
#pragma unroll
      for (int r = 0; r < 4; ++r) {
        int m = m0 + wm + i * 16 + rbase + r;
        float v = acc[i][j][r] + bs;
        if (MODE == 1) {
          Out[(size_t)m * N + ncol] = v;
        } else {
          int b = m >> 11, s = m & 2047;          // S = 2048
          int t = ncol >> 10, nn = ncol & 1023;   // 0:Q 1:K 2:V
          int h = nn >> 6, d = nn & 63;
          size_t bh = (size_t)b * NH + h;
          if (t == 0)      Qb[(bh * S_LEN + s) * DH + d] = (bf16_t)v;
          else if (t == 1) Kb[(bh * S_LEN + s) * DH + d] = (bf16_t)v;
          else             Vt[(bh * DH + d) * S_LEN + s] = (bf16_t)v;
        }
      }
    }
}

// ---------------- per-(b,h) mean of V over all S keys (all-masked-row fallback) ------
__global__ __launch_bounds__(256)
void k_vmean(const bf16_t* __restrict__ Vt, float* __restrict__ vmean) {
  const int bh = blockIdx.x;
  const int t = threadIdx.x;
  const int d = t >> 2, q = t & 3;
  const bf16_t* vp = Vt + ((size_t)bh * DH + d) * S_LEN + q * 512;
  float s = 0.f;
  for (int i = 0; i < 512; i += 8) {
    bf16x8_t v = *reinterpret_cast<const bf16x8_t*>(&vp[i]);
    for (int j = 0; j < 8; ++j) s += (float)v[j];
  }
  __shared__ float part[256];
  part[t] = s;
  __syncthreads();
  if (q == 0)
    vmean[bh * DH + d] = (part[t] + part[t + 1] + part[t + 2] + part[t + 3]) * (1.f / 2048.f);
}

// ---------------- flash attention, swapped-operand, QBLK=32/wave, K reg-dbuf --------
// S^T = mfma(K,Q): softmax state lane-local in q (4 shuffles / 64 keys / frag).
// O^T = mfma(V,P) with consistent in-lane k-permutation on P and V fragments.
// Two 16-row q-fragments per wave share every K/V fragment (2x MFMA per load).
// K register double-buffer: next tile's K loads issue before softmax/PV of the
// current tile; V loads issue before softmax. No LDS, no barriers.
__global__ __launch_bounds__(256, 2)
void k_attn(const bf16_t* __restrict__ Qb, const bf16_t* __restrict__ Kb,
            const bf16_t* __restrict__ Vt, const float* __restrict__ mskf,
            const float* __restrict__ vmean, bf16_t* __restrict__ ctxb) {
  const int tid = threadIdx.x, lane = tid & 63, w = tid >> 6;
  const int bh = blockIdx.x, b = bh >> 4, h = bh & 15;   // bh fast => K/V L2-resident per XCD
  const int qtg = blockIdx.y;
  // balanced wave->qtile pairing: every block totals 66 k-tiles
  const int qt = (w == 0) ? qtg : (w == 1) ? 63 - qtg : (w == 2) ? 16 + qtg : 47 - qtg;
  const int qbase = qt * 32;
  const int l15 = lane & 15, lg = lane >> 4;
  const int qg0 = qbase + l15, qg1 = qbase + 16 + l15;
  const bf16_t* Qp = Qb + (size_t)bh * S_LEN * DH;
  const bf16_t* Kp = Kb + (size_t)bh * S_LEN * DH;
  const bf16_t* Vp = Vt + (size_t)bh * DH * S_LEN;
  const float* mp = mskf + b * S_LEN;

  const bf16x8_t qA0 = *reinterpret_cast<const bf16x8_t*>(&Qp[qg0 * DH + 8 * lg]);
  const bf16x8_t qA1 = *reinterpret_cast<const bf16x8_t*>(&Qp[qg0 * DH + 32 + 8 * lg]);
  const bf16x8_t qB0 = *reinterpret_cast<const bf16x8_t*>(&Qp[qg1 * DH + 8 * lg]);
  const bf16x8_t qB1 = *reinterpret_cast<const bf16x8_t*>(&Qp[qg1 * DH + 32 + 8 * lg]);

  f32x4_t poA[4] = {}, poB[4] = {};
  float mA = -1.9e8f, lA = 0.f;
  float mB = -1.9e8f, lB = 0.f;

  const int ntiles = (qbase + 32 + 63) >> 6;

  // preload K tile 0
  bf16x8_t kc0[4], kc1[4];
#pragma unroll
  for (int t = 0; t < 4; ++t) {
    const bf16_t* kr = &Kp[(t * 16 + l15) * DH + 8 * lg];
    kc0[t] = *reinterpret_cast<const bf16x8_t*>(kr);
    kc1[t] = *reinterpret_cast<const bf16x8_t*>(kr + 32);
  }

  for (int it = 0; it < ntiles; ++it) {
    const int kb = it * 64;
    // ---- QK^T for both q-fragments (K fragments reused) ----
    f32x4_t stA[4], stB[4];
#pragma unroll
    for (int t = 0; t < 4; ++t) {
      f32x4_t s = {};
      s = MFMA(kc0[t], qA0, s);
      s = MFMA(kc1[t], qA1, s);
      stA[t] = s;
      f32x4_t s2 = {};
      s2 = MFMA(kc0[t], qB0, s2);
      s2 = MFMA(kc1[t], qB1, s2);
      stB[t] = s2;
    }
    // ---- issue next-tile K loads now (latency hides under softmax+PV) ----
    const int pkb = (it + 1 < ntiles) ? kb + 64 : 0;   // clamped; dead data ok
    bf16x8_t kn0[4], kn1[4];
#pragma unroll
    for (int t = 0; t < 4; ++t) {
      const bf16_t* kr = &Kp[(pkb + t * 16 + l15) * DH + 8 * lg];
      kn0[t] = *reinterpret_cast<const bf16x8_t*>(kr);
      kn1[t] = *reinterpret_cast<const bf16x8_t*>(kr + 32);
    }
    // ---- issue current-tile V loads (latency hides under softmax) ----
    bf16x8_t vf[2][4];
#pragma unroll
    for (int g = 0; g < 2; ++g)
#pragma unroll
      for (int f = 0; f < 4; ++f) {
        const bf16_t* vr = Vp + (size_t)(f * 16 + l15) * S_LEN + kb + 32 * g + lg * 4;
        bf16x4_t va = *reinterpret_cast<const bf16x4_t*>(vr);
        bf16x4_t vb = *reinterpret_cast<const bf16x4_t*>(vr + 16);
        bf16x8_t vv = {va[0], va[1], va[2], va[3], vb[0], vb[1], vb[2], vb[3]};
        vf[g][f] = vv;
      }
    // ---- mask + scale (log2 domain); mask columns shared by both frags ----
    f32x4_t mk[4];
#pragma unroll
    for (int t = 0; t < 4; ++t)
      mk[t] = *reinterpret_cast<const f32x4_t*>(&mp[kb + t * 16 + lg * 4]);

    const bool nfA = (kb + 63 > qbase);
    const bool nfB = (kb + 63 > qbase + 16);
    float pA[16], pB[16];
    float pmaxA = -3.0e38f, pmaxB = -3.0e38f;
#pragma unroll
    for (int t = 0; t < 4; ++t)
#pragma unroll
      for (int r = 0; r < 4; ++r) {
        const int k = kb + t * 16 + lg * 4 + r;
        float vA = fmaf(stA[t][r], SCL, mk[t][r]);
        float vB = fmaf(stB[t][r], SCL, mk[t][r]);
        if (nfA) vA = (k <= qg0) ? vA : EPS2;
        if (nfB) vB = (k <= qg1) ? vB : EPS2;
        pA[t * 4 + r] = vA;
        pB[t * 4 + r] = vB;
        pmaxA = fmaxf(pmaxA, vA);
        pmaxB = fmaxf(pmaxB, vB);
      }
    pmaxA = fmaxf(pmaxA, __shfl_xor(pmaxA, 16));
    pmaxA = fmaxf(pmaxA, __shfl_xor(pmaxA, 32));
    pmaxB = fmaxf(pmaxB, __shfl_xor(pmaxB, 16));
    pmaxB = fmaxf(pmaxB, __shfl_xor(pmaxB, 32));
    // ---- online softmax (per-lane, q = l15) ----
    const float mnA = fmaxf(mA, pmaxA), mnB = fmaxf(mB, pmaxB);
    const float scA = exp2f(mA - mnA), scB = exp2f(mB - mnB);
    mA = mnA; mB = mnB;
    float psA = 0.f, psB = 0.f;
    bf16_t pbA[16], pbB[16];
#pragma unroll
    for (int i = 0; i < 16; ++i) {
      float eA = exp2f(pA[i] - mnA);
      float eB = exp2f(pB[i] - mnB);
      psA += eA; psB += eB;
      pbA[i] = (bf16_t)eA; pbB[i] = (bf16_t)eB;
    }
    psA += __shfl_xor(psA, 16); psA += __shfl_xor(psA, 32);
    psB += __shfl_xor(psB, 16); psB += __shfl_xor(psB, 32);
    lA = lA * scA + psA;
    lB = lB * scB + psB;
#pragma unroll
    for (int f = 0; f < 4; ++f) { poA[f] *= scA; poB[f] *= scB; }
    // ---- P fragments (in-lane k-permutation, same order as V gather) ----
    bf16x8_t pfA[2], pfB[2];
#pragma unroll
    for (int g = 0; g < 2; ++g) {
      bf16x8_t vA, vB;
#pragma unroll
      for (int j = 0; j < 4; ++j) {
        vA[j] = pbA[(2 * g) * 4 + j];     vA[4 + j] = pbA[(2 * g + 1) * 4 + j];
        vB[j] = pbB[(2 * g) * 4 + j];     vB[4 + j] = pbB[(2 * g + 1) * 4 + j];
      }
      pfA[g] = vA; pfB[g] = vB;
    }
    // ---- PV (V fragments reused by both frags) ----
#pragma unroll
    for (int g = 0; g < 2; ++g)
#pragma unroll
      for (int f = 0; f < 4; ++f) {
        poA[f] = MFMA(vf[g][f], pfA[g], poA[f]);
        poB[f] = MFMA(vf[g][f], pfB[g], poB[f]);
      }
    // ---- rotate K double-buffer ----
#pragma unroll
    for (int t = 0; t < 4; ++t) { kc0[t] = kn0[t]; kc1[t] = kn1[t]; }
  }

  // ---- epilogue: normalize; all-masked rows -> uniform mean of V ----
  const float* vm = vmean + bh * DH;
  {
    const bool dead = (mA < -1.0e7f);
    const float inv = dead ? 0.f : 1.0f / lA;
    bf16_t* orow = ctxb + (size_t)(b * S_LEN + qg0) * DMODEL + h * DH;
#pragma unroll
    for (int f = 0; f < 4; ++f) {
      bf16x4_t o;
#pragma unroll
      for (int r = 0; r < 4; ++r) {
        int d = f * 16 + lg * 4 + r;
        o[r] = (bf16_t)(dead ? vm[d] : poA[f][r] * inv);
      }
      *reinterpret_cast<bf16x4_t*>(&orow[f * 16 + lg * 4]) = o;
    }
  }
  {
    const bool dead = (mB < -1.0e7f);
    const float inv = dead ? 0.f : 1.0f / lB;
    bf16_t* orow = ctxb + (size_t)(b * S_LEN + qg1) * DMODEL + h * DH;
#pragma unroll
    for (int f = 0; f < 4; ++f) {
      bf16x4_t o;
#pragma unroll
      for (int r = 0; r < 4; ++r) {
        int d = f * 16 + lg * 4 + r;
        o[r] = (bf16_t)(dead ? vm[d] : poB[f][r] * inv);
      }
      *reinterpret_cast<bf16x4_t*>(&orow[f * 16 + lg * 4]) = o;
    }
  }
}

extern "C" void kernel_launch(void* const* d_in, const int* in_sizes, int n_in,
                              void* d_out, int out_size, void* d_ws, size_t ws_size,
                              hipStream_t stream) {
  const float* x     = (const float*)d_in[0];
  const int*   amask = (const int*)d_in[1];
  const float* Wqkv  = (const float*)d_in[2];
  const float* bqkv  = (const float*)d_in[3];
  const float* Wproj = (const float*)d_in[4];
  const float* bproj = (const float*)d_in[5];
  float* out = (float*)d_out;

  char* ws = (char*)d_ws;
  bf16_t* xb    = (bf16_t*)(ws);                      // 8 MB  [4096][1024]
  bf16_t* WqT   = (bf16_t*)(ws + (8llu  << 20));      // 6 MB  [3072][1024]
  bf16_t* WpT   = (bf16_t*)(ws + (14llu << 20));      // 2 MB  [1024][1024]
  bf16_t* Qb    = (bf16_t*)(ws + (16llu << 20));      // 8 MB  [b,h,s,d]
  bf16_t* Kb    = (bf16_t*)(ws + (24llu << 20));      // 8 MB  [b,h,s,d]
  bf16_t* Vt    = (bf16_t*)(ws + (32llu << 20));      // 8 MB  [b,h,d,s]
  bf16_t* ctxb  = (bf16_t*)(ws + (40llu << 20));      // 8 MB  [4096][1024]
  float*  vmean = (float*) (ws + (48llu << 20));      // 8 KB  [32][64]
  float*  mskf  = (float*) (ws + (48llu << 20) + 65536);  // 16 KB [2][2048]

  k_cvt_bf16<<<4096, 256, 0, stream>>>(x, xb, (2 * S_LEN * DMODEL) / 4);
  k_mask<<<16, 256, 0, stream>>>(amask, mskf, 2 * S_LEN);
  k_transpose_bf16<<<dim3(3072 / 32, 1024 / 32), dim3(32, 8), 0, stream>>>(Wqkv, WqT, 1024, 3072);
  k_transpose_bf16<<<dim3(1024 / 32, 1024 / 32), dim3(32, 8), 0, stream>>>(Wproj, WpT, 1024, 1024);
  k_gemm<0><<<dim3(3072 / 128, 4096 / 128), 256, 0, stream>>>(
      xb, WqT, bqkv, Qb, Kb, Vt, nullptr, 4096, 3072, 1024);
  k_vmean<<<32, 256, 0, stream>>>(Vt, vmean);
  k_attn<<<dim3(32, 16), 256, 0, stream>>>(Qb, Kb, Vt, mskf, vmean, ctxb);
  k_gemm<1><<<dim3(1024 / 128, 4096 / 128), 256, 0, stream>>>(
      ctxb, WpT, bproj, nullptr, nullptr, nullptr, out, 4096, 1024, 1024);
}

// Round 4
// 182.299 us; speedup vs baseline: 1.9229x; 1.2636x over previous
//
#include <hip/hip_runtime.h>
#include <hip/hip_bf16.h>
#include <stdint.h>

typedef __bf16 bf16_t;
typedef __bf16 bf16x4_t __attribute__((ext_vector_type(4)));
typedef __bf16 bf16x8_t __attribute__((ext_vector_type(8)));
typedef float f32x4_t __attribute__((ext_vector_type(4)));

#define S_LEN   2048
#define DMODEL  1024
#define NH      16
#define DH      64
// masks applied BEFORE scaling: masked logit = -1e9/8; work in log2 domain.
#define LOG2E   1.4426950408889634f
#define SCL     (0.125f * LOG2E)            // st * SCL == (st/8)*log2(e)
#define EPS2    (-1.8033688e8f)             // (-1e9/8) * log2(e)

#define MFMA(a, b, c) __builtin_amdgcn_mfma_f32_16x16x32_bf16(a, b, c, 0, 0, 0)

#define GLOAD_LDS16(gsrc, ldst)                                         \
  __builtin_amdgcn_global_load_lds(                                     \
      (__attribute__((address_space(1))) void*)(void*)(gsrc),           \
      (__attribute__((address_space(3))) void*)(void*)(ldst), 16, 0, 0)

// ---------------- fp32 -> bf16 convert (x) ----------------
__global__ void k_cvt_bf16(const float* __restrict__ in, bf16_t* __restrict__ out, int n4) {
  int i = blockIdx.x * blockDim.x + threadIdx.x;
  if (i >= n4) return;
  float4 v = reinterpret_cast<const float4*>(in)[i];
  bf16x4_t o = {(bf16_t)v.x, (bf16_t)v.y, (bf16_t)v.z, (bf16_t)v.w};
  reinterpret_cast<bf16x4_t*>(out)[i] = o;
}

// ---------------- pad mask -> additive log2-domain float ----------------
__global__ void k_mask(const int* __restrict__ am, float* __restrict__ mskf, int n) {
  int i = blockIdx.x * blockDim.x + threadIdx.x;
  if (i < n) mskf[i] = am[i] ? 0.f : EPS2;
}

// ---------------- fp32 [R][C] -> bf16 [C][R] (weight transpose) ----------------
__global__ void k_transpose_bf16(const float* __restrict__ in, bf16_t* __restrict__ out,
                                 int R, int C) {
  __shared__ float tile[32][33];
  int c0 = blockIdx.x * 32, r0 = blockIdx.y * 32;
  int tx = threadIdx.x, ty = threadIdx.y;   // block (32,8)
  for (int i = ty; i < 32; i += 8)
    tile[i][tx] = in[(size_t)(r0 + i) * C + (c0 + tx)];
  __syncthreads();
  for (int i = ty; i < 32; i += 8)
    out[(size_t)(c0 + i) * R + (r0 + tx)] = (bf16_t)tile[tx][i];
}

// ---------------- bf16 GEMM: C[M][N] = A[M][K] * Bt[N][K]^T + bias ----------------
template<int MODE>
__global__ __launch_bounds__(256)
void k_gemm(const bf16_t* __restrict__ A, const bf16_t* __restrict__ Bt,
            const float* __restrict__ bias,
            bf16_t* __restrict__ Qb, bf16_t* __restrict__ Kb, bf16_t* __restrict__ Vt,
            float* __restrict__ Out, int M, int N, int K) {
  __shared__ alignas(16) bf16_t As[128 * 64];
  __shared__ alignas(16) bf16_t Bs[128 * 64];
  const int tid = threadIdx.x;
  const int lane = tid & 63;
  const int w = tid >> 6;
  const int m0 = blockIdx.y * 128;
  const int n0 = blockIdx.x * 128;
  const int wm = (w >> 1) * 64, wn = (w & 1) * 64;
  const int l15 = lane & 15, lg = lane >> 4;
  const int lrow = lane >> 3;          // 0..7
  const int lcol = (lane & 7) * 8;     // elems

  f32x4_t acc[4][4] = {};

  for (int k0 = 0; k0 < K; k0 += 64) {
    __syncthreads();
#pragma unroll
    for (int p = 0; p < 4; ++p) {
      const int rb = p * 32 + w * 8;   // wave-uniform row base
      GLOAD_LDS16(&A [(size_t)(m0 + rb + lrow) * K + k0 + lcol], &As[rb * 64]);
      GLOAD_LDS16(&Bt[(size_t)(n0 + rb + lrow) * K + k0 + lcol], &Bs[rb * 64]);
    }
    __syncthreads();   // barrier drains vmcnt
#pragma unroll
    for (int kk = 0; kk < 64; kk += 32) {
      bf16x8_t a[4], b[4];
      const int kof = kk + 8 * lg;
#pragma unroll
      for (int i = 0; i < 4; ++i)
        a[i] = *reinterpret_cast<const bf16x8_t*>(&As[(wm + i * 16 + l15) * 64 + kof]);
#pragma unroll
      for (int j = 0; j < 4; ++j)
        b[j] = *reinterpret_cast<const bf16x8_t*>(&Bs[(wn + j * 16 + l15) * 64 + kof]);
#pragma unroll
      for (int i = 0; i < 4; ++i)
#pragma unroll
        for (int j = 0; j < 4; ++j)
          acc[i][j] = MFMA(a[i], b[j], acc[i][j]);
    }
  }

  const int rbase = lg * 4;
#pragma unroll
  for (int i = 0; i < 4; ++i)
#pragma unroll
    for (int j = 0; j < 4; ++j) {
      int ncol = n0 + wn + j * 16 + l15;
      float bs = bias[ncol];
#pragma unroll
      for (int r = 0; r < 4; ++r) {
        int m = m0 + wm + i * 16 + rbase + r;
        float v = acc[i][j][r] + bs;
        if (MODE == 1) {
          Out[(size_t)m * N + ncol] = v;
        } else {
          int b = m >> 11, s = m & 2047;          // S = 2048
          int t = ncol >> 10, nn = ncol & 1023;   // 0:Q 1:K 2:V
          int h = nn >> 6, d = nn & 63;
          size_t bh = (size_t)b * NH + h;
          if (t == 0)      Qb[(bh * S_LEN + s) * DH + d] = (bf16_t)v;
          else if (t == 1) Kb[(bh * S_LEN + s) * DH + d] = (bf16_t)v;
          else             Vt[(bh * DH + d) * S_LEN + s] = (bf16_t)v;
        }
      }
    }
}

// ---------------- per-(b,h) mean of V over all S keys (all-masked-row fallback) ------
__global__ __launch_bounds__(256)
void k_vmean(const bf16_t* __restrict__ Vt, float* __restrict__ vmean) {
  const int bh = blockIdx.x;
  const int t = threadIdx.x;
  const int d = t >> 2, q = t & 3;
  const bf16_t* vp = Vt + ((size_t)bh * DH + d) * S_LEN + q * 512;
  float s = 0.f;
  for (int i = 0; i < 512; i += 8) {
    bf16x8_t v = *reinterpret_cast<const bf16x8_t*>(&vp[i]);
    for (int j = 0; j < 8; ++j) s += (float)v[j];
  }
  __shared__ float part[256];
  part[t] = s;
  __syncthreads();
  if (q == 0)
    vmean[bh * DH + d] = (part[t] + part[t + 1] + part[t + 2] + part[t + 3]) * (1.f / 2048.f);
}

// ---------------- flash attention: block-cooperative LDS K/V, swapped-operand -------
// Block = 4 waves x 32 q-rows = 128 q-rows, all sharing the same k-range.
// K tile [64 keys][64 d] and V^T tile [64 d][64 keys] (8 KB each) staged to LDS
// by global_load_lds (dest linear), with the XOR-16 bank swizzle applied to the
// per-lane GLOBAL source address (LDS[row][c] holds G[row][c ^ 16*(row&7)]).
// Double-buffered; stage of tile t+1 issues right after the barrier that
// publishes tile t, overlapping the whole compute phase.
// S^T = mfma(K,Q) -> softmax lane-local in q. O^T = mfma(V^T,P) with the same
// in-lane k-permutation on P-build and V-fragment reads.
// LPT: qst = 15 - blockIdx.y dispatches heavy blocks first -> CU work balanced.
__global__ __launch_bounds__(256, 2)
void k_attn(const bf16_t* __restrict__ Qb, const bf16_t* __restrict__ Kb,
            const bf16_t* __restrict__ Vt, const float* __restrict__ mskf,
            const float* __restrict__ vmean, bf16_t* __restrict__ ctxb) {
  __shared__ alignas(16) char smem[32768];   // Ks0 Ks1 Vs0 Vs1, 8 KB each
  const int tid = threadIdx.x, lane = tid & 63, w = tid >> 6;
  const int bh = blockIdx.x, b = bh >> 4, h = bh & 15;  // bh fast => K/V L2-resident
  const int qst = 15 - blockIdx.y;                      // heavy-first (LPT)
  const int qbase = qst * 128 + w * 32;
  const int l15 = lane & 15, lg = lane >> 4;
  const int qg0 = qbase + l15, qg1 = qbase + 16 + l15;
  const bf16_t* Qp = Qb + (size_t)bh * S_LEN * DH;
  const char*   Kg = (const char*)(Kb + (size_t)bh * S_LEN * DH);  // row = key, 128 B
  const char*   Vg = (const char*)(Vt + (size_t)bh * DH * S_LEN);  // row = d, 4096 B
  const float*  mp = mskf + b * S_LEN;

  // staging lane constants: lane covers row srow (of 8), pre-swizzled source col
  const int srow = lane >> 3;
  const int scol = ((lane & 7) * 16) ^ (srow * 16);
  const int swz  = 16 * (l15 & 7);

  const bf16x8_t qA0 = *reinterpret_cast<const bf16x8_t*>(&Qp[qg0 * DH + 8 * lg]);
  const bf16x8_t qA1 = *reinterpret_cast<const bf16x8_t*>(&Qp[qg0 * DH + 32 + 8 * lg]);
  const bf16x8_t qB0 = *reinterpret_cast<const bf16x8_t*>(&Qp[qg1 * DH + 8 * lg]);
  const bf16x8_t qB1 = *reinterpret_cast<const bf16x8_t*>(&Qp[qg1 * DH + 32 + 8 * lg]);

  f32x4_t poA[4] = {}, poB[4] = {};
  float mA = -1.9e8f, lA = 0.f;
  float mB = -1.9e8f, lB = 0.f;

  const int nt = 2 * (qst + 1);   // k-tiles of 64 for this block

  // stage tile it into buffer buf: wave w stages rows w*16..w*16+15 of K and V^T
#define STAGE_TILE(it_, buf_)                                                      \
  do {                                                                             \
    const int kb_ = (it_) * 64;                                                    \
    _Pragma("unroll")                                                              \
    for (int j = 0; j < 2; ++j) {                                                  \
      const int r_ = w * 16 + j * 8;                                               \
      GLOAD_LDS16(Kg + (size_t)(kb_ + r_ + srow) * 128 + scol,                     \
                  smem + (buf_) * 8192 + r_ * 128);                                \
      GLOAD_LDS16(Vg + (size_t)(r_ + srow) * 4096 + (size_t)kb_ * 2 + scol,       \
                  smem + 16384 + (buf_) * 8192 + r_ * 128);                        \
    }                                                                              \
  } while (0)

  STAGE_TILE(0, 0);

  for (int it = 0; it < nt; ++it) {
    const int kb = it * 64;
    const int buf = it & 1;
    __syncthreads();                       // publishes tile it; frees buf^1
    if (it + 1 < nt) STAGE_TILE(it + 1, buf ^ 1);   // async, drains at next barrier
    if (kb > qbase + 31) continue;         // wave-uniform causal skip (stage+barrier only)

    const char* Ksb = smem + buf * 8192;
    const char* Vsb = smem + 16384 + buf * 8192;

    // ---- QK^T (swapped): st[t][r] = S[k=kb+t*16+lg*4+r][q] ----
    f32x4_t stA[4], stB[4];
#pragma unroll
    for (int t = 0; t < 4; ++t) {
      const int rbyte = (t * 16 + l15) * 128;
      bf16x8_t k0 = *reinterpret_cast<const bf16x8_t*>(Ksb + rbyte + ((16 * lg) ^ swz));
      bf16x8_t k1 = *reinterpret_cast<const bf16x8_t*>(Ksb + rbyte + ((64 + 16 * lg) ^ swz));
      f32x4_t s = {};
      s = MFMA(k0, qA0, s);
      s = MFMA(k1, qA1, s);
      stA[t] = s;
      f32x4_t s2 = {};
      s2 = MFMA(k0, qB0, s2);
      s2 = MFMA(k1, qB1, s2);
      stB[t] = s2;
    }
    // ---- mask + scale (log2 domain) ----
    f32x4_t mk[4];
#pragma unroll
    for (int t = 0; t < 4; ++t)
      mk[t] = *reinterpret_cast<const f32x4_t*>(&mp[kb + t * 16 + lg * 4]);

    const bool nfA = (kb + 63 > qbase);
    const bool nfB = (kb + 63 > qbase + 16);
    float pA[16], pB[16];
    float pmaxA = -3.0e38f, pmaxB = -3.0e38f;
#pragma unroll
    for (int t = 0; t < 4; ++t)
#pragma unroll
      for (int r = 0; r < 4; ++r) {
        const int k = kb + t * 16 + lg * 4 + r;
        float vA = fmaf(stA[t][r], SCL, mk[t][r]);
        float vB = fmaf(stB[t][r], SCL, mk[t][r]);
        if (nfA) vA = (k <= qg0) ? vA : EPS2;
        if (nfB) vB = (k <= qg1) ? vB : EPS2;
        pA[t * 4 + r] = vA;
        pB[t * 4 + r] = vB;
        pmaxA = fmaxf(pmaxA, vA);
        pmaxB = fmaxf(pmaxB, vB);
      }
    pmaxA = fmaxf(pmaxA, __shfl_xor(pmaxA, 16));
    pmaxA = fmaxf(pmaxA, __shfl_xor(pmaxA, 32));
    pmaxB = fmaxf(pmaxB, __shfl_xor(pmaxB, 16));
    pmaxB = fmaxf(pmaxB, __shfl_xor(pmaxB, 32));
    // ---- online softmax (per-lane, q = l15) ----
    const float mnA = fmaxf(mA, pmaxA), mnB = fmaxf(mB, pmaxB);
    const float scA = exp2f(mA - mnA), scB = exp2f(mB - mnB);
    mA = mnA; mB = mnB;
    float psA = 0.f, psB = 0.f;
    bf16_t pbA[16], pbB[16];
#pragma unroll
    for (int i = 0; i < 16; ++i) {
      float eA = exp2f(pA[i] - mnA);
      float eB = exp2f(pB[i] - mnB);
      psA += eA; psB += eB;
      pbA[i] = (bf16_t)eA; pbB[i] = (bf16_t)eB;
    }
    psA += __shfl_xor(psA, 16); psA += __shfl_xor(psA, 32);
    psB += __shfl_xor(psB, 16); psB += __shfl_xor(psB, 32);
    lA = lA * scA + psA;
    lB = lB * scB + psB;
#pragma unroll
    for (int f = 0; f < 4; ++f) { poA[f] *= scA; poB[f] *= scB; }
    // ---- P fragments (in-lane k-permutation, matches V-fragment read) ----
    bf16x8_t pfA[2], pfB[2];
#pragma unroll
    for (int g = 0; g < 2; ++g) {
      bf16x8_t vA, vB;
#pragma unroll
      for (int j = 0; j < 4; ++j) {
        vA[j] = pbA[(2 * g) * 4 + j];     vA[4 + j] = pbA[(2 * g + 1) * 4 + j];
        vB[j] = pbB[(2 * g) * 4 + j];     vB[4 + j] = pbB[(2 * g + 1) * 4 + j];
      }
      pfA[g] = vA; pfB[g] = vB;
    }
    // ---- PV: V^T fragments from LDS (b64 pairs, same k-permutation) ----
#pragma unroll
    for (int g = 0; g < 2; ++g)
#pragma unroll
      for (int f = 0; f < 4; ++f) {
        const int rbyte = (f * 16 + l15) * 128;
        bf16x4_t va = *reinterpret_cast<const bf16x4_t*>(
            Vsb + rbyte + ((64 * g + 8 * lg) ^ swz));
        bf16x4_t vb = *reinterpret_cast<const bf16x4_t*>(
            Vsb + rbyte + ((64 * g + 32 + 8 * lg) ^ swz));
        bf16x8_t vv = {va[0], va[1], va[2], va[3], vb[0], vb[1], vb[2], vb[3]};
        poA[f] = MFMA(vv, pfA[g], poA[f]);
        poB[f] = MFMA(vv, pfB[g], poB[f]);
      }
  }
#undef STAGE_TILE

  // ---- epilogue: normalize; all-masked rows -> uniform mean of V ----
  const float* vm = vmean + bh * DH;
  {
    const bool dead = (mA < -1.0e7f);
    const float inv = dead ? 0.f : 1.0f / lA;
    bf16_t* orow = ctxb + (size_t)(b * S_LEN + qg0) * DMODEL + h * DH;
#pragma unroll
    for (int f = 0; f < 4; ++f) {
      bf16x4_t o;
#pragma unroll
      for (int r = 0; r < 4; ++r) {
        int d = f * 16 + lg * 4 + r;
        o[r] = (bf16_t)(dead ? vm[d] : poA[f][r] * inv);
      }
      *reinterpret_cast<bf16x4_t*>(&orow[f * 16 + lg * 4]) = o;
    }
  }
  {
    const bool dead = (mB < -1.0e7f);
    const float inv = dead ? 0.f : 1.0f / lB;
    bf16_t* orow = ctxb + (size_t)(b * S_LEN + qg1) * DMODEL + h * DH;
#pragma unroll
    for (int f = 0; f < 4; ++f) {
      bf16x4_t o;
#pragma unroll
      for (int r = 0; r < 4; ++r) {
        int d = f * 16 + lg * 4 + r;
        o[r] = (bf16_t)(dead ? vm[d] : poB[f][r] * inv);
      }
      *reinterpret_cast<bf16x4_t*>(&orow[f * 16 + lg * 4]) = o;
    }
  }
}

extern "C" void kernel_launch(void* const* d_in, const int* in_sizes, int n_in,
                              void* d_out, int out_size, void* d_ws, size_t ws_size,
                              hipStream_t stream) {
  const float* x     = (const float*)d_in[0];
  const int*   amask = (const int*)d_in[1];
  const float* Wqkv  = (const float*)d_in[2];
  const float* bqkv  = (const float*)d_in[3];
  const float* Wproj = (const float*)d_in[4];
  const float* bproj = (const float*)d_in[5];
  float* out = (float*)d_out;

  char* ws = (char*)d_ws;
  bf16_t* xb    = (bf16_t*)(ws);                      // 8 MB  [4096][1024]
  bf16_t* WqT   = (bf16_t*)(ws + (8llu  << 20));      // 6 MB  [3072][1024]
  bf16_t* WpT   = (bf16_t*)(ws + (14llu << 20));      // 2 MB  [1024][1024]
  bf16_t* Qb    = (bf16_t*)(ws + (16llu << 20));      // 8 MB  [b,h,s,d]
  bf16_t* Kb    = (bf16_t*)(ws + (24llu << 20));      // 8 MB  [b,h,s,d]
  bf16_t* Vt    = (bf16_t*)(ws + (32llu << 20));      // 8 MB  [b,h,d,s]
  bf16_t* ctxb  = (bf16_t*)(ws + (40llu << 20));      // 8 MB  [4096][1024]
  float*  vmean = (float*) (ws + (48llu << 20));      // 8 KB  [32][64]
  float*  mskf  = (float*) (ws + (48llu << 20) + 65536);  // 16 KB [2][2048]

  k_cvt_bf16<<<4096, 256, 0, stream>>>(x, xb, (2 * S_LEN * DMODEL) / 4);
  k_mask<<<16, 256, 0, stream>>>(amask, mskf, 2 * S_LEN);
  k_transpose_bf16<<<dim3(3072 / 32, 1024 / 32), dim3(32, 8), 0, stream>>>(Wqkv, WqT, 1024, 3072);
  k_transpose_bf16<<<dim3(1024 / 32, 1024 / 32), dim3(32, 8), 0, stream>>>(Wproj, WpT, 1024, 1024);
  k_gemm<0><<<dim3(3072 / 128, 4096 / 128), 256, 0, stream>>>(
      xb, WqT, bqkv, Qb, Kb, Vt, nullptr, 4096, 3072, 1024);
  k_vmean<<<32, 256, 0, stream>>>(Vt, vmean);
  k_attn<<<dim3(32, 16), 256, 0, stream>>>(Qb, Kb, Vt, mskf, vmean, ctxb);
  k_gemm<1><<<dim3(1024 / 128, 4096 / 128), 256, 0, stream>>>(
      ctxb, WpT, bproj, nullptr, nullptr, nullptr, out, 4096, 1024, 1024);
}

// Round 5
// 182.056 us; speedup vs baseline: 1.9254x; 1.0013x over previous
//
#include <hip/hip_runtime.h>
#include <hip/hip_bf16.h>
#include <stdint.h>

typedef __bf16 bf16_t;
typedef __bf16 bf16x4_t __attribute__((ext_vector_type(4)));
typedef __bf16 bf16x8_t __attribute__((ext_vector_type(8)));
typedef float f32x4_t __attribute__((ext_vector_type(4)));

#define S_LEN   2048
#define DMODEL  1024
#define NH      16
#define DH      64
// masks applied BEFORE scaling: masked logit = -1e9/8; work in log2 domain.
#define LOG2E   1.4426950408889634f
#define SCL     (0.125f * LOG2E)            // st * SCL == (st/8)*log2(e)
#define EPS2    (-1.8033688e8f)             // (-1e9/8) * log2(e)

#define MFMA(a, b, c) __builtin_amdgcn_mfma_f32_16x16x32_bf16(a, b, c, 0, 0, 0)

#define GLOAD_LDS16(gsrc, ldst)                                         \
  __builtin_amdgcn_global_load_lds(                                     \
      (__attribute__((address_space(1))) void*)(void*)(gsrc),           \
      (__attribute__((address_space(3))) void*)(void*)(ldst), 16, 0, 0)

// ---------------- fp32 -> bf16 convert (x) ----------------
__global__ void k_cvt_bf16(const float* __restrict__ in, bf16_t* __restrict__ out, int n4) {
  int i = blockIdx.x * blockDim.x + threadIdx.x;
  if (i >= n4) return;
  float4 v = reinterpret_cast<const float4*>(in)[i];
  bf16x4_t o = {(bf16_t)v.x, (bf16_t)v.y, (bf16_t)v.z, (bf16_t)v.w};
  reinterpret_cast<bf16x4_t*>(out)[i] = o;
}

// ---------------- pad mask -> additive log2-domain float ----------------
__global__ void k_mask(const int* __restrict__ am, float* __restrict__ mskf, int n) {
  int i = blockIdx.x * blockDim.x + threadIdx.x;
  if (i < n) mskf[i] = am[i] ? 0.f : EPS2;
}

// ---------------- fp32 [R][C] -> bf16 [C][R] (weight transpose) ----------------
__global__ void k_transpose_bf16(const float* __restrict__ in, bf16_t* __restrict__ out,
                                 int R, int C) {
  __shared__ float tile[32][33];
  int c0 = blockIdx.x * 32, r0 = blockIdx.y * 32;
  int tx = threadIdx.x, ty = threadIdx.y;   // block (32,8)
  for (int i = ty; i < 32; i += 8)
    tile[i][tx] = in[(size_t)(r0 + i) * C + (c0 + tx)];
  __syncthreads();
  for (int i = ty; i < 32; i += 8)
    out[(size_t)(c0 + i) * R + (r0 + tx)] = (bf16_t)tile[tx][i];
}

// ---------------- bf16 GEMM: C[M][N] = A[M][K] * Bt[N][K]^T + bias ----------------
// T3-minimum 2-phase pipeline: LDS double-buffer; STAGE(t+1) issues BEFORE
// compute(t); single __syncthreads per iter (its vmcnt(0) drains the prefetch
// that overlapped the whole compute phase).
template<int MODE>
__global__ __launch_bounds__(256)
void k_gemm(const bf16_t* __restrict__ A, const bf16_t* __restrict__ Bt,
            const float* __restrict__ bias,
            bf16_t* __restrict__ Qb, bf16_t* __restrict__ Kb, bf16_t* __restrict__ Vt,
            float* __restrict__ Out, int M, int N, int K) {
  __shared__ alignas(16) bf16_t As[2][128 * 64];
  __shared__ alignas(16) bf16_t Bs[2][128 * 64];
  const int tid = threadIdx.x;
  const int lane = tid & 63;
  const int w = tid >> 6;
  const int m0 = blockIdx.y * 128;
  const int n0 = blockIdx.x * 128;
  const int wm = (w >> 1) * 64, wn = (w & 1) * 64;
  const int l15 = lane & 15, lg = lane >> 4;
  const int lrow = lane >> 3;          // 0..7
  const int lcol = (lane & 7) * 8;     // elems

  f32x4_t acc[4][4] = {};

#define GSTAGE(k0_, buf_)                                                        \
  do {                                                                           \
    _Pragma("unroll")                                                            \
    for (int p = 0; p < 4; ++p) {                                                \
      const int rb = p * 32 + w * 8;   /* wave-uniform row base */               \
      GLOAD_LDS16(&A [(size_t)(m0 + rb + lrow) * K + (k0_) + lcol],              \
                  &As[buf_][rb * 64]);                                           \
      GLOAD_LDS16(&Bt[(size_t)(n0 + rb + lrow) * K + (k0_) + lcol],              \
                  &Bs[buf_][rb * 64]);                                           \
    }                                                                            \
  } while (0)

  GSTAGE(0, 0);
  __syncthreads();                       // drains stage(0)
  int buf = 0;
  for (int k0 = 0; k0 < K; k0 += 64) {
    if (k0 + 64 < K) GSTAGE(k0 + 64, buf ^ 1);   // overlaps compute below
    const bf16_t* Asb = As[buf];
    const bf16_t* Bsb = Bs[buf];
#pragma unroll
    for (int kk = 0; kk < 64; kk += 32) {
      bf16x8_t a[4], b[4];
      const int kof = kk + 8 * lg;
#pragma unroll
      for (int i = 0; i < 4; ++i)
        a[i] = *reinterpret_cast<const bf16x8_t*>(&Asb[(wm + i * 16 + l15) * 64 + kof]);
#pragma unroll
      for (int j = 0; j < 4; ++j)
        b[j] = *reinterpret_cast<const bf16x8_t*>(&Bsb[(wn + j * 16 + l15) * 64 + kof]);
      __builtin_amdgcn_s_setprio(1);
#pragma unroll
      for (int i = 0; i < 4; ++i)
#pragma unroll
        for (int j = 0; j < 4; ++j)
          acc[i][j] = MFMA(a[i], b[j], acc[i][j]);
      __builtin_amdgcn_s_setprio(0);
    }
    __syncthreads();                     // drains stage(t+1); frees buf for t+2
    buf ^= 1;
  }
#undef GSTAGE

  const int rbase = lg * 4;
#pragma unroll
  for (int i = 0; i < 4; ++i)
#pragma unroll
    for (int j = 0; j < 4; ++j) {
      int ncol = n0 + wn + j * 16 + l15;
      float bs = bias[ncol];
#pragma unroll
      for (int r = 0; r < 4; ++r) {
        int m = m0 + wm + i * 16 + rbase + r;
        float v = acc[i][j][r] + bs;
        if (MODE == 1) {
          Out[(size_t)m * N + ncol] = v;
        } else {
          int b = m >> 11, s = m & 2047;          // S = 2048
          int t = ncol >> 10, nn = ncol & 1023;   // 0:Q 1:K 2:V
          int h = nn >> 6, d = nn & 63;
          size_t bh = (size_t)b * NH + h;
          if (t == 0)      Qb[(bh * S_LEN + s) * DH + d] = (bf16_t)v;
          else if (t == 1) Kb[(bh * S_LEN + s) * DH + d] = (bf16_t)v;
          else             Vt[(bh * DH + d) * S_LEN + s] = (bf16_t)v;
        }
      }
    }
}

// ---------------- per-(b,h) mean of V over all S keys (all-masked-row fallback) ------
__global__ __launch_bounds__(256)
void k_vmean(const bf16_t* __restrict__ Vt, float* __restrict__ vmean) {
  const int bh = blockIdx.x;
  const int t = threadIdx.x;
  const int d = t >> 2, q = t & 3;
  const bf16_t* vp = Vt + ((size_t)bh * DH + d) * S_LEN + q * 512;
  float s = 0.f;
  for (int i = 0; i < 512; i += 8) {
    bf16x8_t v = *reinterpret_cast<const bf16x8_t*>(&vp[i]);
    for (int j = 0; j < 8; ++j) s += (float)v[j];
  }
  __shared__ float part[256];
  part[t] = s;
  __syncthreads();
  if (q == 0)
    vmean[bh * DH + d] = (part[t] + part[t + 1] + part[t + 2] + part[t + 3]) * (1.f / 2048.f);
}

// ---------------- flash attention: block-cooperative LDS K/V, swapped-operand -------
// Block = 4 waves x 32 q-rows = 128 q-rows sharing one k-range. K tile and V^T
// tile staged by global_load_lds with XOR-16 source pre-swizzle; double-buffered.
// S^T = mfma(K,Q) -> softmax lane-local in q; O^T = mfma(V^T,P) with consistent
// in-lane k-permutation. Stripe remap: co-resident block pairs (c, c+256) get
// complementary causal lengths -> every CU totals 34 tile-units (static LPT).
__global__ __launch_bounds__(256, 2)
void k_attn(const bf16_t* __restrict__ Qb, const bf16_t* __restrict__ Kb,
            const bf16_t* __restrict__ Vt, const float* __restrict__ mskf,
            const float* __restrict__ vmean, bf16_t* __restrict__ ctxb) {
  __shared__ alignas(16) char smem[32768];   // Ks0 Ks1 Vs0 Vs1, 8 KB each
  const int tid = threadIdx.x, lane = tid & 63, w = tid >> 6;
  const int bh = blockIdx.x, b = bh >> 4, h = bh & 15;  // bh fast => K/V L2-resident
  const int y = blockIdx.y;
  const int qst = (y < 8) ? (15 - 2 * y) : (2 * (y - 8));  // pair-balanced stripes
  const int qbase = qst * 128 + w * 32;
  const int l15 = lane & 15, lg = lane >> 4;
  const int qg0 = qbase + l15, qg1 = qbase + 16 + l15;
  const bf16_t* Qp = Qb + (size_t)bh * S_LEN * DH;
  const char*   Kg = (const char*)(Kb + (size_t)bh * S_LEN * DH);  // row = key, 128 B
  const char*   Vg = (const char*)(Vt + (size_t)bh * DH * S_LEN);  // row = d, 4096 B
  const float*  mp = mskf + b * S_LEN;

  // staging lane constants: lane covers row srow (of 8), pre-swizzled source col
  const int srow = lane >> 3;
  const int scol = ((lane & 7) * 16) ^ (srow * 16);
  const int swz  = 16 * (l15 & 7);

  const bf16x8_t qA0 = *reinterpret_cast<const bf16x8_t*>(&Qp[qg0 * DH + 8 * lg]);
  const bf16x8_t qA1 = *reinterpret_cast<const bf16x8_t*>(&Qp[qg0 * DH + 32 + 8 * lg]);
  const bf16x8_t qB0 = *reinterpret_cast<const bf16x8_t*>(&Qp[qg1 * DH + 8 * lg]);
  const bf16x8_t qB1 = *reinterpret_cast<const bf16x8_t*>(&Qp[qg1 * DH + 32 + 8 * lg]);

  f32x4_t poA[4] = {}, poB[4] = {};
  float mA = -1.9e8f, lA = 0.f;
  float mB = -1.9e8f, lB = 0.f;

  const int nt = 2 * (qst + 1);   // k-tiles of 64 for this block

#define STAGE_TILE(it_, buf_)                                                      \
  do {                                                                             \
    const int kb_ = (it_) * 64;                                                    \
    _Pragma("unroll")                                                              \
    for (int j = 0; j < 2; ++j) {                                                  \
      const int r_ = w * 16 + j * 8;                                               \
      GLOAD_LDS16(Kg + (size_t)(kb_ + r_ + srow) * 128 + scol,                     \
                  smem + (buf_) * 8192 + r_ * 128);                                \
      GLOAD_LDS16(Vg + (size_t)(r_ + srow) * 4096 + (size_t)kb_ * 2 + scol,       \
                  smem + 16384 + (buf_) * 8192 + r_ * 128);                        \
    }                                                                              \
  } while (0)

  STAGE_TILE(0, 0);

  for (int it = 0; it < nt; ++it) {
    const int kb = it * 64;
    const int buf = it & 1;
    __syncthreads();                       // publishes tile it; frees buf^1
    if (it + 1 < nt) STAGE_TILE(it + 1, buf ^ 1);   // async, drains at next barrier
    if (kb > qbase + 31) continue;         // wave-uniform causal skip (stage+barrier only)

    const char* Ksb = smem + buf * 8192;
    const char* Vsb = smem + 16384 + buf * 8192;

    // ---- mask vectors first: global loads fly under the MFMA cluster ----
    f32x4_t mk[4];
#pragma unroll
    for (int t = 0; t < 4; ++t)
      mk[t] = *reinterpret_cast<const f32x4_t*>(&mp[kb + t * 16 + lg * 4]);

    // ---- QK^T (swapped): st[t][r] = S[k=kb+t*16+lg*4+r][q] ----
    f32x4_t stA[4], stB[4];
    __builtin_amdgcn_s_setprio(1);
#pragma unroll
    for (int t = 0; t < 4; ++t) {
      const int rbyte = (t * 16 + l15) * 128;
      bf16x8_t k0 = *reinterpret_cast<const bf16x8_t*>(Ksb + rbyte + ((16 * lg) ^ swz));
      bf16x8_t k1 = *reinterpret_cast<const bf16x8_t*>(Ksb + rbyte + ((64 + 16 * lg) ^ swz));
      f32x4_t s = {};
      s = MFMA(k0, qA0, s);
      s = MFMA(k1, qA1, s);
      stA[t] = s;
      f32x4_t s2 = {};
      s2 = MFMA(k0, qB0, s2);
      s2 = MFMA(k1, qB1, s2);
      stB[t] = s2;
    }
    __builtin_amdgcn_s_setprio(0);

    const bool nfA = (kb + 63 > qbase);
    const bool nfB = (kb + 63 > qbase + 16);
    float pA[16], pB[16];
    float pmaxA = -3.0e38f, pmaxB = -3.0e38f;
#pragma unroll
    for (int t = 0; t < 4; ++t)
#pragma unroll
      for (int r = 0; r < 4; ++r) {
        const int k = kb + t * 16 + lg * 4 + r;
        float vA = fmaf(stA[t][r], SCL, mk[t][r]);
        float vB = fmaf(stB[t][r], SCL, mk[t][r]);
        if (nfA) vA = (k <= qg0) ? vA : EPS2;
        if (nfB) vB = (k <= qg1) ? vB : EPS2;
        pA[t * 4 + r] = vA;
        pB[t * 4 + r] = vB;
        pmaxA = fmaxf(pmaxA, vA);
        pmaxB = fmaxf(pmaxB, vB);
      }
    pmaxA = fmaxf(pmaxA, __shfl_xor(pmaxA, 16));
    pmaxA = fmaxf(pmaxA, __shfl_xor(pmaxA, 32));
    pmaxB = fmaxf(pmaxB, __shfl_xor(pmaxB, 16));
    pmaxB = fmaxf(pmaxB, __shfl_xor(pmaxB, 32));
    // ---- online softmax with defer-max (T13): skip rescale if growth <= 8 ----
    if (!__all(pmaxA <= mA + 8.f)) {
      const float mn = fmaxf(mA, pmaxA);
      const float sc = exp2f(mA - mn);
      mA = mn; lA *= sc;
#pragma unroll
      for (int f = 0; f < 4; ++f) poA[f] *= sc;
    }
    if (!__all(pmaxB <= mB + 8.f)) {
      const float mn = fmaxf(mB, pmaxB);
      const float sc = exp2f(mB - mn);
      mB = mn; lB *= sc;
#pragma unroll
      for (int f = 0; f < 4; ++f) poB[f] *= sc;
    }
    float psA = 0.f, psB = 0.f;
    bf16_t pbA[16], pbB[16];
#pragma unroll
    for (int i = 0; i < 16; ++i) {
      float eA = exp2f(pA[i] - mA);
      float eB = exp2f(pB[i] - mB);
      psA += eA; psB += eB;
      pbA[i] = (bf16_t)eA; pbB[i] = (bf16_t)eB;
    }
    psA += __shfl_xor(psA, 16); psA += __shfl_xor(psA, 32);
    psB += __shfl_xor(psB, 16); psB += __shfl_xor(psB, 32);
    lA += psA;
    lB += psB;
    // ---- P fragments (in-lane k-permutation, matches V-fragment read) ----
    bf16x8_t pfA[2], pfB[2];
#pragma unroll
    for (int g = 0; g < 2; ++g) {
      bf16x8_t vA, vB;
#pragma unroll
      for (int j = 0; j < 4; ++j) {
        vA[j] = pbA[(2 * g) * 4 + j];     vA[4 + j] = pbA[(2 * g + 1) * 4 + j];
        vB[j] = pbB[(2 * g) * 4 + j];     vB[4 + j] = pbB[(2 * g + 1) * 4 + j];
      }
      pfA[g] = vA; pfB[g] = vB;
    }
    // ---- PV: V^T fragments from LDS (b64 pairs, same k-permutation) ----
    __builtin_amdgcn_s_setprio(1);
#pragma unroll
    for (int g = 0; g < 2; ++g)
#pragma unroll
      for (int f = 0; f < 4; ++f) {
        const int rbyte = (f * 16 + l15) * 128;
        bf16x4_t va = *reinterpret_cast<const bf16x4_t*>(
            Vsb + rbyte + ((64 * g + 8 * lg) ^ swz));
        bf16x4_t vb = *reinterpret_cast<const bf16x4_t*>(
            Vsb + rbyte + ((64 * g + 32 + 8 * lg) ^ swz));
        bf16x8_t vv = {va[0], va[1], va[2], va[3], vb[0], vb[1], vb[2], vb[3]};
        poA[f] = MFMA(vv, pfA[g], poA[f]);
        poB[f] = MFMA(vv, pfB[g], poB[f]);
      }
    __builtin_amdgcn_s_setprio(0);
  }
#undef STAGE_TILE

  // ---- epilogue: normalize; all-masked rows -> uniform mean of V ----
  const float* vm = vmean + bh * DH;
  {
    const bool dead = (mA < -1.0e7f);
    const float inv = dead ? 0.f : 1.0f / lA;
    bf16_t* orow = ctxb + (size_t)(b * S_LEN + qg0) * DMODEL + h * DH;
#pragma unroll
    for (int f = 0; f < 4; ++f) {
      bf16x4_t o;
#pragma unroll
      for (int r = 0; r < 4; ++r) {
        int d = f * 16 + lg * 4 + r;
        o[r] = (bf16_t)(dead ? vm[d] : poA[f][r] * inv);
      }
      *reinterpret_cast<bf16x4_t*>(&orow[f * 16 + lg * 4]) = o;
    }
  }
  {
    const bool dead = (mB < -1.0e7f);
    const float inv = dead ? 0.f : 1.0f / lB;
    bf16_t* orow = ctxb + (size_t)(b * S_LEN + qg1) * DMODEL + h * DH;
#pragma unroll
    for (int f = 0; f < 4; ++f) {
      bf16x4_t o;
#pragma unroll
      for (int r = 0; r < 4; ++r) {
        int d = f * 16 + lg * 4 + r;
        o[r] = (bf16_t)(dead ? vm[d] : poB[f][r] * inv);
      }
      *reinterpret_cast<bf16x4_t*>(&orow[f * 16 + lg * 4]) = o;
    }
  }
}

extern "C" void kernel_launch(void* const* d_in, const int* in_sizes, int n_in,
                              void* d_out, int out_size, void* d_ws, size_t ws_size,
                              hipStream_t stream) {
  const float* x     = (const float*)d_in[0];
  const int*   amask = (const int*)d_in[1];
  const float* Wqkv  = (const float*)d_in[2];
  const float* bqkv  = (const float*)d_in[3];
  const float* Wproj = (const float*)d_in[4];
  const float* bproj = (const float*)d_in[5];
  float* out = (float*)d_out;

  char* ws = (char*)d_ws;
  bf16_t* xb    = (bf16_t*)(ws);                      // 8 MB  [4096][1024]
  bf16_t* WqT   = (bf16_t*)(ws + (8llu  << 20));      // 6 MB  [3072][1024]
  bf16_t* WpT   = (bf16_t*)(ws + (14llu << 20));      // 2 MB  [1024][1024]
  bf16_t* Qb    = (bf16_t*)(ws + (16llu << 20));      // 8 MB  [b,h,s,d]
  bf16_t* Kb    = (bf16_t*)(ws + (24llu << 20));      // 8 MB  [b,h,s,d]
  bf16_t* Vt    = (bf16_t*)(ws + (32llu << 20));      // 8 MB  [b,h,d,s]
  bf16_t* ctxb  = (bf16_t*)(ws + (40llu << 20));      // 8 MB  [4096][1024]
  float*  vmean = (float*) (ws + (48llu << 20));      // 8 KB  [32][64]
  float*  mskf  = (float*) (ws + (48llu << 20) + 65536);  // 16 KB [2][2048]

  k_cvt_bf16<<<4096, 256, 0, stream>>>(x, xb, (2 * S_LEN * DMODEL) / 4);
  k_mask<<<16, 256, 0, stream>>>(amask, mskf, 2 * S_LEN);
  k_transpose_bf16<<<dim3(3072 / 32, 1024 / 32), dim3(32, 8), 0, stream>>>(Wqkv, WqT, 1024, 3072);
  k_transpose_bf16<<<dim3(1024 / 32, 1024 / 32), dim3(32, 8), 0, stream>>>(Wproj, WpT, 1024, 1024);
  k_gemm<0><<<dim3(3072 / 128, 4096 / 128), 256, 0, stream>>>(
      xb, WqT, bqkv, Qb, Kb, Vt, nullptr, 4096, 3072, 1024);
  k_vmean<<<32, 256, 0, stream>>>(Vt, vmean);
  k_attn<<<dim3(32, 16), 256, 0, stream>>>(Qb, Kb, Vt, mskf, vmean, ctxb);
  k_gemm<1><<<dim3(1024 / 128, 4096 / 128), 256, 0, stream>>>(
      ctxb, WpT, bproj, nullptr, nullptr, nullptr, out, 4096, 1024, 1024);
}

// Round 6
// 170.890 us; speedup vs baseline: 2.0513x; 1.0653x over previous
//
#include <hip/hip_runtime.h>
#include <hip/hip_bf16.h>
#include <stdint.h>

typedef __bf16 bf16_t;
typedef __bf16 bf16x4_t __attribute__((ext_vector_type(4)));
typedef __bf16 bf16x8_t __attribute__((ext_vector_type(8)));
typedef float f32x4_t __attribute__((ext_vector_type(4)));

#define S_LEN   2048
#define DMODEL  1024
#define NH      16
#define DH      64
// masks applied BEFORE scaling: masked logit = -1e9/8; work in log2 domain.
#define LOG2E   1.4426950408889634f
#define SCL     (0.125f * LOG2E)            // st * SCL == (st/8)*log2(e)
#define EPS2    (-1.8033688e8f)             // (-1e9/8) * log2(e)

#define MFMA(a, b, c) __builtin_amdgcn_mfma_f32_16x16x32_bf16(a, b, c, 0, 0, 0)

#define GLOAD_LDS16(gsrc, ldst)                                         \
  __builtin_amdgcn_global_load_lds(                                     \
      (__attribute__((address_space(1))) void*)(void*)(gsrc),           \
      (__attribute__((address_space(3))) void*)(void*)(ldst), 16, 0, 0)

// ---------------- fp32 -> bf16 convert (x) ----------------
__global__ void k_cvt_bf16(const float* __restrict__ in, bf16_t* __restrict__ out, int n4) {
  int i = blockIdx.x * blockDim.x + threadIdx.x;
  if (i >= n4) return;
  float4 v = reinterpret_cast<const float4*>(in)[i];
  bf16x4_t o = {(bf16_t)v.x, (bf16_t)v.y, (bf16_t)v.z, (bf16_t)v.w};
  reinterpret_cast<bf16x4_t*>(out)[i] = o;
}

// ---------------- pad mask -> additive log2-domain float ----------------
__global__ void k_mask(const int* __restrict__ am, float* __restrict__ mskf, int n) {
  int i = blockIdx.x * blockDim.x + threadIdx.x;
  if (i < n) mskf[i] = am[i] ? 0.f : EPS2;
}

// ---------------- fp32 [R][C] -> bf16 [C][R] (weight transpose) ----------------
__global__ void k_transpose_bf16(const float* __restrict__ in, bf16_t* __restrict__ out,
                                 int R, int C) {
  __shared__ float tile[32][33];
  int c0 = blockIdx.x * 32, r0 = blockIdx.y * 32;
  int tx = threadIdx.x, ty = threadIdx.y;   // block (32,8)
  for (int i = ty; i < 32; i += 8)
    tile[i][tx] = in[(size_t)(r0 + i) * C + (c0 + tx)];
  __syncthreads();
  for (int i = ty; i < 32; i += 8)
    out[(size_t)(c0 + i) * R + (r0 + tx)] = (bf16_t)tile[tx][i];
}

// ---------------- bf16 GEMM: C[M][N] = A[M][K] * Bt[N][K]^T + bias ----------------
// 2-phase LDS double-buffer; STAGE(t+1) before compute(t). T1 XCD swizzle.
template<int MODE>
__global__ __launch_bounds__(256)
void k_gemm(const bf16_t* __restrict__ A, const bf16_t* __restrict__ Bt,
            const float* __restrict__ bias,
            bf16_t* __restrict__ Qb, bf16_t* __restrict__ Kb, bf16_t* __restrict__ Vt,
            float* __restrict__ Out, int M, int N, int K) {
  __shared__ alignas(16) bf16_t As[2][128 * 64];
  __shared__ alignas(16) bf16_t Bs[2][128 * 64];
  const int tid = threadIdx.x;
  const int lane = tid & 63;
  const int w = tid >> 6;
  // T1: XCD-aware bijective swizzle (nwg % 8 == 0 for both call sites)
  const int nwg = gridDim.x * gridDim.y;
  int lin = blockIdx.y * gridDim.x + blockIdx.x;
  lin = (lin & 7) * (nwg >> 3) + (lin >> 3);
  const int m0 = (lin / gridDim.x) * 128;
  const int n0 = (lin % gridDim.x) * 128;
  const int wm = (w >> 1) * 64, wn = (w & 1) * 64;
  const int l15 = lane & 15, lg = lane >> 4;
  const int lrow = lane >> 3;          // 0..7
  const int lcol = (lane & 7) * 8;     // elems

  f32x4_t acc[4][4] = {};

#define GSTAGE(k0_, buf_)                                                        \
  do {                                                                           \
    _Pragma("unroll")                                                            \
    for (int p = 0; p < 4; ++p) {                                                \
      const int rb = p * 32 + w * 8;   /* wave-uniform row base */               \
      GLOAD_LDS16(&A [(size_t)(m0 + rb + lrow) * K + (k0_) + lcol],              \
                  &As[buf_][rb * 64]);                                           \
      GLOAD_LDS16(&Bt[(size_t)(n0 + rb + lrow) * K + (k0_) + lcol],              \
                  &Bs[buf_][rb * 64]);                                           \
    }                                                                            \
  } while (0)

  GSTAGE(0, 0);
  __syncthreads();                       // drains stage(0)
  int buf = 0;
  for (int k0 = 0; k0 < K; k0 += 64) {
    if (k0 + 64 < K) GSTAGE(k0 + 64, buf ^ 1);   // overlaps compute below
    const bf16_t* Asb = As[buf];
    const bf16_t* Bsb = Bs[buf];
#pragma unroll
    for (int kk = 0; kk < 64; kk += 32) {
      bf16x8_t a[4], b[4];
      const int kof = kk + 8 * lg;
#pragma unroll
      for (int i = 0; i < 4; ++i)
        a[i] = *reinterpret_cast<const bf16x8_t*>(&Asb[(wm + i * 16 + l15) * 64 + kof]);
#pragma unroll
      for (int j = 0; j < 4; ++j)
        b[j] = *reinterpret_cast<const bf16x8_t*>(&Bsb[(wn + j * 16 + l15) * 64 + kof]);
      __builtin_amdgcn_s_setprio(1);
#pragma unroll
      for (int i = 0; i < 4; ++i)
#pragma unroll
        for (int j = 0; j < 4; ++j)
          acc[i][j] = MFMA(a[i], b[j], acc[i][j]);
      __builtin_amdgcn_s_setprio(0);
    }
    __syncthreads();                     // drains stage(t+1); frees buf for t+2
    buf ^= 1;
  }
#undef GSTAGE

  const int rbase = lg * 4;
#pragma unroll
  for (int i = 0; i < 4; ++i)
#pragma unroll
    for (int j = 0; j < 4; ++j) {
      int ncol = n0 + wn + j * 16 + l15;
      float bs = bias[ncol];
#pragma unroll
      for (int r = 0; r < 4; ++r) {
        int m = m0 + wm + i * 16 + rbase + r;
        float v = acc[i][j][r] + bs;
        if (MODE == 1) {
          Out[(size_t)m * N + ncol] = v;
        } else {
          int b = m >> 11, s = m & 2047;          // S = 2048
          int t = ncol >> 10, nn = ncol & 1023;   // 0:Q 1:K 2:V
          int h = nn >> 6, d = nn & 63;
          size_t bh = (size_t)b * NH + h;
          if (t == 0)      Qb[(bh * S_LEN + s) * DH + d] = (bf16_t)v;
          else if (t == 1) Kb[(bh * S_LEN + s) * DH + d] = (bf16_t)v;
          else             Vt[(bh * DH + d) * S_LEN + s] = (bf16_t)v;
        }
      }
    }
}

// ---------------- per-(b,h) mean of V over all S keys (all-masked-row fallback) ------
__global__ __launch_bounds__(256)
void k_vmean(const bf16_t* __restrict__ Vt, float* __restrict__ vmean) {
  const int bh = blockIdx.x;
  const int t = threadIdx.x;
  const int d = t >> 2, q = t & 3;
  const bf16_t* vp = Vt + ((size_t)bh * DH + d) * S_LEN + q * 512;
  float s = 0.f;
  for (int i = 0; i < 512; i += 8) {
    bf16x8_t v = *reinterpret_cast<const bf16x8_t*>(&vp[i]);
    for (int j = 0; j < 8; ++j) s += (float)v[j];
  }
  __shared__ float part[256];
  part[t] = s;
  __syncthreads();
  if (q == 0)
    vmean[bh * DH + d] = (part[t] + part[t + 1] + part[t + 2] + part[t + 3]) * (1.f / 2048.f);
}

// ---------------- flash attention: 128-key phases, interleaved subtiles -------------
// Block = 4 waves x 32 q-rows = 128 q-rows sharing one k-range. Per phase: 128 keys
// staged to LDS (K 16KB + V^T 16KB, XOR-16 source pre-swizzle, double-buffered).
// Per phase: QK(s0) -> QK(s1) -> SM(s0) -> PV(s0) -> SM(s1) -> PV(s1): QK1 MFMAs
// overlap SM0 VALU; PV0 overlaps SM1. Full phases have NO causal ops (diagonal
// phase peeled). P->bf16 via v_cvt_pk_bf16_f32 (2 floats/op, kills hidden RNE
// cast bloat). Softmax lane-local in q (swapped QK^T); defer-max (T13).
__global__ __launch_bounds__(256, 2)
void k_attn(const bf16_t* __restrict__ Qb, const bf16_t* __restrict__ Kb,
            const bf16_t* __restrict__ Vt, const float* __restrict__ mskf,
            const float* __restrict__ vmean, bf16_t* __restrict__ ctxb) {
  __shared__ alignas(16) char smem[65536];   // K: 2 x 16KB @0; V^T: 2 x 16KB @32768
  const int tid = threadIdx.x, lane = tid & 63, w = tid >> 6;
  const int bh = blockIdx.x, b = bh >> 4, h = bh & 15;  // bh fast => K/V L2-resident
  const int y = blockIdx.y;
  const int qst = (y < 8) ? (15 - 2 * y) : (2 * (y - 8));  // pair-balanced stripes
  const int qbase = qst * 128 + w * 32;
  const int l15 = lane & 15, lg = lane >> 4;
  const int qg0 = qbase + l15, qg1 = qbase + 16 + l15;
  const bf16_t* Qp = Qb + (size_t)bh * S_LEN * DH;
  const char*   Kg = (const char*)(Kb + (size_t)bh * S_LEN * DH);  // row = key, 128 B
  const char*   Vg = (const char*)(Vt + (size_t)bh * DH * S_LEN);  // row = d, 4096 B
  const float*  mp = mskf + b * S_LEN;

  // staging lane constants (pre-swizzled global source cols, 16B units)
  const int srow = lane >> 3;                               // K: 8 rows/iter
  const int scol = ((lane & 7) * 16) ^ (srow * 16);
  const int vrow = lane >> 4;                               // V: 4 rows/iter
  const int swz  = 16 * (l15 & 7);

  const bf16x8_t qA0 = *reinterpret_cast<const bf16x8_t*>(&Qp[qg0 * DH + 8 * lg]);
  const bf16x8_t qA1 = *reinterpret_cast<const bf16x8_t*>(&Qp[qg0 * DH + 32 + 8 * lg]);
  const bf16x8_t qB0 = *reinterpret_cast<const bf16x8_t*>(&Qp[qg1 * DH + 8 * lg]);
  const bf16x8_t qB1 = *reinterpret_cast<const bf16x8_t*>(&Qp[qg1 * DH + 32 + 8 * lg]);

  f32x4_t poA[4] = {}, poB[4] = {};
  float mA = -1.9e8f, lA = 0.f;
  float mB = -1.9e8f, lB = 0.f;

  // stage phase ph_ (128 keys) into buffer buf_
#define STAGE_PH(ph_, buf_)                                                        \
  do {                                                                             \
    const int kb_ = (ph_) * 128;                                                   \
    _Pragma("unroll")                                                              \
    for (int j = 0; j < 4; ++j) {                                                  \
      const int rk = w * 32 + j * 8;                                               \
      GLOAD_LDS16(Kg + (size_t)(kb_ + rk + srow) * 128 + scol,                     \
                  smem + (buf_) * 16384 + rk * 128);                               \
      const int rv = w * 16 + j * 4;                                               \
      const int vc = ((lane & 15) * 16) ^ ((((j << 2) + vrow) & 7) * 16);          \
      GLOAD_LDS16(Vg + (size_t)(rv + vrow) * 4096 + (size_t)kb_ * 2 + vc,          \
                  smem + 32768 + (buf_) * 16384 + rv * 256);                       \
    }                                                                              \
  } while (0)

  // QK^T for 64-key subtile S_: stX[t][r] = S[k = kb + S_*64 + t*16 + lg*4+r][q]
#define QK_SUB(S_, STA, STB)                                                       \
  _Pragma("unroll")                                                                \
  for (int t = 0; t < 4; ++t) {                                                    \
    const int rbyte = ((S_) * 64 + t * 16 + l15) * 128;                            \
    bf16x8_t k0 = *reinterpret_cast<const bf16x8_t*>(Ksb + rbyte + ((16 * lg) ^ swz));       \
    bf16x8_t k1 = *reinterpret_cast<const bf16x8_t*>(Ksb + rbyte + ((64 + 16 * lg) ^ swz));  \
    f32x4_t s = {}; s = MFMA(k0, qA0, s); s = MFMA(k1, qA1, s); STA[t] = s;        \
    f32x4_t s2 = {}; s2 = MFMA(k0, qB0, s2); s2 = MFMA(k1, qB1, s2); STB[t] = s2;  \
  }

  // softmax + pack: ST[4] f32x4 logits -> PF[2] bf16x8; updates M, L, PO (defer-max)
#define SM_PACK(ST, MK, M_, L_, PO, PF, QG, CAUSAL, KB0)                           \
  do {                                                                             \
    float e[16]; float pmax = -3.0e38f;                                            \
    _Pragma("unroll")                                                              \
    for (int t = 0; t < 4; ++t)                                                    \
      _Pragma("unroll")                                                            \
      for (int r = 0; r < 4; ++r) {                                                \
        float v = fmaf(ST[t][r], SCL, MK[t][r]);                                   \
        if (CAUSAL) {                                                              \
          int k = (KB0) + t * 16 + lg * 4 + r;                                     \
          v = (k <= (QG)) ? v : EPS2;                                              \
        }                                                                          \
        e[t * 4 + r] = v; pmax = fmaxf(pmax, v);                                   \
      }                                                                            \
    pmax = fmaxf(pmax, __shfl_xor(pmax, 16));                                      \
    pmax = fmaxf(pmax, __shfl_xor(pmax, 32));                                      \
    if (!__all(pmax <= (M_) + 8.f)) {                                              \
      float mn = fmaxf(M_, pmax); float sc = exp2f((M_) - mn);                     \
      M_ = mn; L_ *= sc;                                                           \
      _Pragma("unroll") for (int f = 0; f < 4; ++f) PO[f] *= sc;                   \
    }                                                                              \
    float ps = 0.f;                                                                \
    _Pragma("unroll")                                                              \
    for (int i = 0; i < 16; ++i) { e[i] = exp2f(e[i] - (M_)); ps += e[i]; }        \
    ps += __shfl_xor(ps, 16); ps += __shfl_xor(ps, 32);                            \
    L_ += ps;                                                                      \
    _Pragma("unroll")                                                              \
    for (int g = 0; g < 2; ++g) {                                                  \
      union { uint32_t u[4]; bf16x8_t v; } pk_;                                    \
      _Pragma("unroll")                                                            \
      for (int j = 0; j < 4; ++j)                                                  \
        asm("v_cvt_pk_bf16_f32 %0, %1, %2"                                         \
            : "=v"(pk_.u[j]) : "v"(e[8 * g + 2 * j]), "v"(e[8 * g + 2 * j + 1]));  \
      PF[g] = pk_.v;                                                               \
    }                                                                              \
  } while (0)

  // PV for subtile S_: po += V^T x P (in-lane k-permutation matches SM_PACK order)
#define PV_SUB(S_, PFA, PFB)                                                       \
  _Pragma("unroll")                                                                \
  for (int g = 0; g < 2; ++g)                                                      \
    _Pragma("unroll")                                                              \
    for (int f = 0; f < 4; ++f) {                                                  \
      const int rbyte = (f * 16 + l15) * 256;                                      \
      const int cb = (S_) * 128 + 64 * g + 8 * lg;                                 \
      bf16x4_t va = *reinterpret_cast<const bf16x4_t*>(Vsb + rbyte + (cb ^ swz));          \
      bf16x4_t vb = *reinterpret_cast<const bf16x4_t*>(Vsb + rbyte + ((cb + 32) ^ swz));   \
      bf16x8_t vv = {va[0], va[1], va[2], va[3], vb[0], vb[1], vb[2], vb[3]};      \
      poA[f] = MFMA(vv, PFA[g], poA[f]);                                           \
      poB[f] = MFMA(vv, PFB[g], poB[f]);                                           \
    }

  int buf = 0;
  STAGE_PH(0, 0);

  // ---- full phases: no causal ops at all ----
  for (int ph = 0; ph < qst; ++ph) {
    const int kb = ph * 128;
    __syncthreads();                         // publishes phase ph; frees buf^1
    STAGE_PH(ph + 1, buf ^ 1);               // async; drains at next barrier
    const char* Ksb = smem + buf * 16384;
    const char* Vsb = smem + 32768 + buf * 16384;

    f32x4_t mk0[4], mk1[4];
#pragma unroll
    for (int t = 0; t < 4; ++t) {
      mk0[t] = *reinterpret_cast<const f32x4_t*>(&mp[kb + t * 16 + lg * 4]);
      mk1[t] = *reinterpret_cast<const f32x4_t*>(&mp[kb + 64 + t * 16 + lg * 4]);
    }

    f32x4_t stA0[4], stB0[4], stA1[4], stB1[4];
    __builtin_amdgcn_s_setprio(1);
    QK_SUB(0, stA0, stB0);
    QK_SUB(1, stA1, stB1);
    __builtin_amdgcn_s_setprio(0);

    bf16x8_t pfA[2], pfB[2];
    SM_PACK(stA0, mk0, mA, lA, poA, pfA, qg0, false, 0);
    SM_PACK(stB0, mk0, mB, lB, poB, pfB, qg1, false, 0);
    __builtin_amdgcn_s_setprio(1);
    PV_SUB(0, pfA, pfB);
    __builtin_amdgcn_s_setprio(0);
    SM_PACK(stA1, mk1, mA, lA, poA, pfA, qg0, false, 0);
    SM_PACK(stB1, mk1, mB, lB, poB, pfB, qg1, false, 0);
    __builtin_amdgcn_s_setprio(1);
    PV_SUB(1, pfA, pfB);
    __builtin_amdgcn_s_setprio(0);
    buf ^= 1;
  }

  // ---- diagonal phase (ph == qst): causal masking; sub1 only for waves 2,3 ----
  {
    const int kb = qst * 128;
    __syncthreads();
    const char* Ksb = smem + buf * 16384;
    const char* Vsb = smem + 32768 + buf * 16384;

    f32x4_t mk0[4], mk1[4];
#pragma unroll
    for (int t = 0; t < 4; ++t) {
      mk0[t] = *reinterpret_cast<const f32x4_t*>(&mp[kb + t * 16 + lg * 4]);
      mk1[t] = *reinterpret_cast<const f32x4_t*>(&mp[kb + 64 + t * 16 + lg * 4]);
    }

    f32x4_t stA0[4], stB0[4], stA1[4], stB1[4];
    bf16x8_t pfA[2], pfB[2];
    QK_SUB(0, stA0, stB0);
    SM_PACK(stA0, mk0, mA, lA, poA, pfA, qg0, true, kb);
    SM_PACK(stB0, mk0, mB, lB, poB, pfB, qg1, true, kb);
    PV_SUB(0, pfA, pfB);
    if (w >= 2) {                          // wave-uniform: sub1 exists only for w>=2
      QK_SUB(1, stA1, stB1);
      SM_PACK(stA1, mk1, mA, lA, poA, pfA, qg0, true, kb + 64);
      SM_PACK(stB1, mk1, mB, lB, poB, pfB, qg1, true, kb + 64);
      PV_SUB(1, pfA, pfB);
    }
  }
#undef STAGE_PH
#undef QK_SUB
#undef SM_PACK
#undef PV_SUB

  // ---- epilogue: normalize; all-masked rows -> uniform mean of V ----
  const float* vm = vmean + bh * DH;
  {
    const bool dead = (mA < -1.0e7f);
    const float inv = dead ? 0.f : 1.0f / lA;
    bf16_t* orow = ctxb + (size_t)(b * S_LEN + qg0) * DMODEL + h * DH;
#pragma unroll
    for (int f = 0; f < 4; ++f) {
      bf16x4_t o;
#pragma unroll
      for (int r = 0; r < 4; ++r) {
        int d = f * 16 + lg * 4 + r;
        o[r] = (bf16_t)(dead ? vm[d] : poA[f][r] * inv);
      }
      *reinterpret_cast<bf16x4_t*>(&orow[f * 16 + lg * 4]) = o;
    }
  }
  {
    const bool dead = (mB < -1.0e7f);
    const float inv = dead ? 0.f : 1.0f / lB;
    bf16_t* orow = ctxb + (size_t)(b * S_LEN + qg1) * DMODEL + h * DH;
#pragma unroll
    for (int f = 0; f < 4; ++f) {
      bf16x4_t o;
#pragma unroll
      for (int r = 0; r < 4; ++r) {
        int d = f * 16 + lg * 4 + r;
        o[r] = (bf16_t)(dead ? vm[d] : poB[f][r] * inv);
      }
      *reinterpret_cast<bf16x4_t*>(&orow[f * 16 + lg * 4]) = o;
    }
  }
}

extern "C" void kernel_launch(void* const* d_in, const int* in_sizes, int n_in,
                              void* d_out, int out_size, void* d_ws, size_t ws_size,
                              hipStream_t stream) {
  const float* x     = (const float*)d_in[0];
  const int*   amask = (const int*)d_in[1];
  const float* Wqkv  = (const float*)d_in[2];
  const float* bqkv  = (const float*)d_in[3];
  const float* Wproj = (const float*)d_in[4];
  const float* bproj = (const float*)d_in[5];
  float* out = (float*)d_out;

  char* ws = (char*)d_ws;
  bf16_t* xb    = (bf16_t*)(ws);                      // 8 MB  [4096][1024]
  bf16_t* WqT   = (bf16_t*)(ws + (8llu  << 20));      // 6 MB  [3072][1024]
  bf16_t* WpT   = (bf16_t*)(ws + (14llu << 20));      // 2 MB  [1024][1024]
  bf16_t* Qb    = (bf16_t*)(ws + (16llu << 20));      // 8 MB  [b,h,s,d]
  bf16_t* Kb    = (bf16_t*)(ws + (24llu << 20));      // 8 MB  [b,h,s,d]
  bf16_t* Vt    = (bf16_t*)(ws + (32llu << 20));      // 8 MB  [b,h,d,s]
  bf16_t* ctxb  = (bf16_t*)(ws + (40llu << 20));      // 8 MB  [4096][1024]
  float*  vmean = (float*) (ws + (48llu << 20));      // 8 KB  [32][64]
  float*  mskf  = (float*) (ws + (48llu << 20) + 65536);  // 16 KB [2][2048]

  k_cvt_bf16<<<4096, 256, 0, stream>>>(x, xb, (2 * S_LEN * DMODEL) / 4);
  k_mask<<<16, 256, 0, stream>>>(amask, mskf, 2 * S_LEN);
  k_transpose_bf16<<<dim3(3072 / 32, 1024 / 32), dim3(32, 8), 0, stream>>>(Wqkv, WqT, 1024, 3072);
  k_transpose_bf16<<<dim3(1024 / 32, 1024 / 32), dim3(32, 8), 0, stream>>>(Wproj, WpT, 1024, 1024);
  k_gemm<0><<<dim3(3072 / 128, 4096 / 128), 256, 0, stream>>>(
      xb, WqT, bqkv, Qb, Kb, Vt, nullptr, 4096, 3072, 1024);
  k_vmean<<<32, 256, 0, stream>>>(Vt, vmean);
  k_attn<<<dim3(32, 16), 256, 0, stream>>>(Qb, Kb, Vt, mskf, vmean, ctxb);
  k_gemm<1><<<dim3(1024 / 128, 4096 / 128), 256, 0, stream>>>(
      ctxb, WpT, bproj, nullptr, nullptr, nullptr, out, 4096, 1024, 1024);
}

// Round 7
// 157.066 us; speedup vs baseline: 2.2318x; 1.0880x over previous
//
#include <hip/hip_runtime.h>
#include <hip/hip_bf16.h>
#include <stdint.h>

typedef __bf16 bf16_t;
typedef __bf16 bf16x4_t __attribute__((ext_vector_type(4)));
typedef __bf16 bf16x8_t __attribute__((ext_vector_type(8)));
typedef float f32x4_t __attribute__((ext_vector_type(4)));

#define S_LEN   2048
#define DMODEL  1024
#define NH      16
#define DH      64
// masks applied BEFORE scaling: masked logit = -1e9/8; work in log2 domain.
#define LOG2E   1.4426950408889634f
#define SCL     (0.125f * LOG2E)            // st * SCL == (st/8)*log2(e)
#define EPS2    (-1.8033688e8f)             // (-1e9/8) * log2(e)

#define MFMA(a, b, c) __builtin_amdgcn_mfma_f32_16x16x32_bf16(a, b, c, 0, 0, 0)

#define GLOAD_LDS16(gsrc, ldst)                                         \
  __builtin_amdgcn_global_load_lds(                                     \
      (__attribute__((address_space(1))) void*)(void*)(gsrc),           \
      (__attribute__((address_space(3))) void*)(void*)(ldst), 16, 0, 0)

// ---------------- fp32 -> bf16 convert (x) ----------------
__global__ void k_cvt_bf16(const float* __restrict__ in, bf16_t* __restrict__ out, int n4) {
  int i = blockIdx.x * blockDim.x + threadIdx.x;
  if (i >= n4) return;
  float4 v = reinterpret_cast<const float4*>(in)[i];
  bf16x4_t o = {(bf16_t)v.x, (bf16_t)v.y, (bf16_t)v.z, (bf16_t)v.w};
  reinterpret_cast<bf16x4_t*>(out)[i] = o;
}

// ---------------- pad mask -> additive log2-domain float ----------------
__global__ void k_mask(const int* __restrict__ am, float* __restrict__ mskf, int n) {
  int i = blockIdx.x * blockDim.x + threadIdx.x;
  if (i < n) mskf[i] = am[i] ? 0.f : EPS2;
}

// ---------------- fp32 [R][C] -> bf16 [C][R] (weight transpose) ----------------
__global__ void k_transpose_bf16(const float* __restrict__ in, bf16_t* __restrict__ out,
                                 int R, int C) {
  __shared__ float tile[32][33];
  int c0 = blockIdx.x * 32, r0 = blockIdx.y * 32;
  int tx = threadIdx.x, ty = threadIdx.y;   // block (32,8)
  for (int i = ty; i < 32; i += 8)
    tile[i][tx] = in[(size_t)(r0 + i) * C + (c0 + tx)];
  __syncthreads();
  for (int i = ty; i < 32; i += 8)
    out[(size_t)(c0 + i) * R + (r0 + tx)] = (bf16_t)tile[tx][i];
}

// ---------------- bf16 GEMM: C[M][N] = A[M][K] * Bt[N][K]^T + bias ----------------
// 2-phase pipeline with T4 counted-vmcnt raw barriers (prefetch stays in flight
// across the barrier; only the PREVIOUS tile's 8 loads are waited) and T2
// both-sides XOR swizzle (pre-swizzled global source col for the linear
// global_load_lds dest; XOR'd ds_read col) -> 16-way bank conflict -> <=2-way.
template<int MODE>
__global__ __launch_bounds__(256)
void k_gemm(const bf16_t* __restrict__ A, const bf16_t* __restrict__ Bt,
            const float* __restrict__ bias,
            bf16_t* __restrict__ Qb, bf16_t* __restrict__ Kb, bf16_t* __restrict__ Vt,
            float* __restrict__ Out, int M, int N, int K) {
  __shared__ alignas(16) bf16_t As[2][128 * 64];
  __shared__ alignas(16) bf16_t Bs[2][128 * 64];
  const int tid = threadIdx.x;
  const int lane = tid & 63;
  const int w = tid >> 6;
  // T1: XCD-aware bijective swizzle (nwg % 8 == 0 for both call sites)
  const int nwg = gridDim.x * gridDim.y;
  int lin = blockIdx.y * gridDim.x + blockIdx.x;
  lin = (lin & 7) * (nwg >> 3) + (lin >> 3);
  const int m0 = (lin / gridDim.x) * 128;
  const int n0 = (lin % gridDim.x) * 128;
  const int wm = (w >> 1) * 64, wn = (w & 1) * 64;
  const int l15 = lane & 15, lg = lane >> 4;
  const int lrow = lane >> 3;                        // 0..7 (row within 8-row stripe)
  const int lcsw = (((lane & 7) ^ lrow) * 8);        // pre-swizzled source col (elems)
  const int swz8 = (l15 & 7) * 8;                    // read-side XOR (elems)

  f32x4_t acc[4][4] = {};

#define GSTAGE(k0_, buf_)                                                        \
  do {                                                                           \
    _Pragma("unroll")                                                            \
    for (int p = 0; p < 4; ++p) {                                                \
      const int rb = p * 32 + w * 8;   /* wave-uniform row base (mult of 8) */   \
      GLOAD_LDS16(&A [(size_t)(m0 + rb + lrow) * K + (k0_) + lcsw],              \
                  &As[buf_][rb * 64]);                                           \
      GLOAD_LDS16(&Bt[(size_t)(n0 + rb + lrow) * K + (k0_) + lcsw],              \
                  &Bs[buf_][rb * 64]);                                           \
    }                                                                            \
  } while (0)

  GSTAGE(0, 0);                          // 8 loads/wave in flight
  int buf = 0;
  for (int k0 = 0; k0 < K; k0 += 64) {
    if (k0 + 64 < K) {
      GSTAGE(k0 + 64, buf ^ 1);          // +8 -> 16 outstanding
      asm volatile("s_waitcnt vmcnt(8)" ::: "memory");   // previous tile landed
    } else {
      asm volatile("s_waitcnt vmcnt(0)" ::: "memory");   // final tile drain
    }
    __builtin_amdgcn_s_barrier();        // raw: prefetch stays in flight
    __builtin_amdgcn_sched_barrier(0);
    const bf16_t* Asb = As[buf];
    const bf16_t* Bsb = Bs[buf];
#pragma unroll
    for (int kk = 0; kk < 64; kk += 32) {
      bf16x8_t a[4], b[4];
      const int kof = kk + 8 * lg;
#pragma unroll
      for (int i = 0; i < 4; ++i)
        a[i] = *reinterpret_cast<const bf16x8_t*>(
            &Asb[(wm + i * 16 + l15) * 64 + (kof ^ swz8)]);
#pragma unroll
      for (int j = 0; j < 4; ++j)
        b[j] = *reinterpret_cast<const bf16x8_t*>(
            &Bsb[(wn + j * 16 + l15) * 64 + (kof ^ swz8)]);
      __builtin_amdgcn_s_setprio(1);
#pragma unroll
      for (int i = 0; i < 4; ++i)
#pragma unroll
        for (int j = 0; j < 4; ++j)
          acc[i][j] = MFMA(a[i], b[j], acc[i][j]);
      __builtin_amdgcn_s_setprio(0);
    }
    __builtin_amdgcn_sched_barrier(0);   // pin reads/MFMAs before the barrier
    __builtin_amdgcn_s_barrier();        // all waves done reading buf
    buf ^= 1;
  }
#undef GSTAGE

  const int rbase = lg * 4;
#pragma unroll
  for (int i = 0; i < 4; ++i)
#pragma unroll
    for (int j = 0; j < 4; ++j) {
      int ncol = n0 + wn + j * 16 + l15;
      float bs = bias[ncol];
#pragma unroll
      for (int r = 0; r < 4; ++r) {
        int m = m0 + wm + i * 16 + rbase + r;
        float v = acc[i][j][r] + bs;
        if (MODE == 1) {
          Out[(size_t)m * N + ncol] = v;
        } else {
          int b = m >> 11, s = m & 2047;          // S = 2048
          int t = ncol >> 10, nn = ncol & 1023;   // 0:Q 1:K 2:V
          int h = nn >> 6, d = nn & 63;
          size_t bh = (size_t)b * NH + h;
          if (t == 0)      Qb[(bh * S_LEN + s) * DH + d] = (bf16_t)v;
          else if (t == 1) Kb[(bh * S_LEN + s) * DH + d] = (bf16_t)v;
          else             Vt[(bh * DH + d) * S_LEN + s] = (bf16_t)v;
        }
      }
    }
}

// ---------------- per-(b,h) mean of V over all S keys (all-masked-row fallback) ------
__global__ __launch_bounds__(256)
void k_vmean(const bf16_t* __restrict__ Vt, float* __restrict__ vmean) {
  const int bh = blockIdx.x;
  const int t = threadIdx.x;
  const int d = t >> 2, q = t & 3;
  const bf16_t* vp = Vt + ((size_t)bh * DH + d) * S_LEN + q * 512;
  float s = 0.f;
  for (int i = 0; i < 512; i += 8) {
    bf16x8_t v = *reinterpret_cast<const bf16x8_t*>(&vp[i]);
    for (int j = 0; j < 8; ++j) s += (float)v[j];
  }
  __shared__ float part[256];
  part[t] = s;
  __syncthreads();
  if (q == 0)
    vmean[bh * DH + d] = (part[t] + part[t + 1] + part[t + 2] + part[t + 3]) * (1.f / 2048.f);
}

// ---------------- flash attention: 128-key phases, interleaved subtiles -------------
// (unchanged from round 6 to isolate the GEMM delta)
__global__ __launch_bounds__(256, 2)
void k_attn(const bf16_t* __restrict__ Qb, const bf16_t* __restrict__ Kb,
            const bf16_t* __restrict__ Vt, const float* __restrict__ mskf,
            const float* __restrict__ vmean, bf16_t* __restrict__ ctxb) {
  __shared__ alignas(16) char smem[65536];   // K: 2 x 16KB @0; V^T: 2 x 16KB @32768
  const int tid = threadIdx.x, lane = tid & 63, w = tid >> 6;
  const int bh = blockIdx.x, b = bh >> 4, h = bh & 15;  // bh fast => K/V L2-resident
  const int y = blockIdx.y;
  const int qst = (y < 8) ? (15 - 2 * y) : (2 * (y - 8));  // pair-balanced stripes
  const int qbase = qst * 128 + w * 32;
  const int l15 = lane & 15, lg = lane >> 4;
  const int qg0 = qbase + l15, qg1 = qbase + 16 + l15;
  const bf16_t* Qp = Qb + (size_t)bh * S_LEN * DH;
  const char*   Kg = (const char*)(Kb + (size_t)bh * S_LEN * DH);  // row = key, 128 B
  const char*   Vg = (const char*)(Vt + (size_t)bh * DH * S_LEN);  // row = d, 4096 B
  const float*  mp = mskf + b * S_LEN;

  // staging lane constants (pre-swizzled global source cols, 16B units)
  const int srow = lane >> 3;                               // K: 8 rows/iter
  const int scol = ((lane & 7) * 16) ^ (srow * 16);
  const int vrow = lane >> 4;                               // V: 4 rows/iter
  const int swz  = 16 * (l15 & 7);

  const bf16x8_t qA0 = *reinterpret_cast<const bf16x8_t*>(&Qp[qg0 * DH + 8 * lg]);
  const bf16x8_t qA1 = *reinterpret_cast<const bf16x8_t*>(&Qp[qg0 * DH + 32 + 8 * lg]);
  const bf16x8_t qB0 = *reinterpret_cast<const bf16x8_t*>(&Qp[qg1 * DH + 8 * lg]);
  const bf16x8_t qB1 = *reinterpret_cast<const bf16x8_t*>(&Qp[qg1 * DH + 32 + 8 * lg]);

  f32x4_t poA[4] = {}, poB[4] = {};
  float mA = -1.9e8f, lA = 0.f;
  float mB = -1.9e8f, lB = 0.f;

  // stage phase ph_ (128 keys) into buffer buf_
#define STAGE_PH(ph_, buf_)                                                        \
  do {                                                                             \
    const int kb_ = (ph_) * 128;                                                   \
    _Pragma("unroll")                                                              \
    for (int j = 0; j < 4; ++j) {                                                  \
      const int rk = w * 32 + j * 8;                                               \
      GLOAD_LDS16(Kg + (size_t)(kb_ + rk + srow) * 128 + scol,                     \
                  smem + (buf_) * 16384 + rk * 128);                               \
      const int rv = w * 16 + j * 4;                                               \
      const int vc = ((lane & 15) * 16) ^ ((((j << 2) + vrow) & 7) * 16);          \
      GLOAD_LDS16(Vg + (size_t)(rv + vrow) * 4096 + (size_t)kb_ * 2 + vc,          \
                  smem + 32768 + (buf_) * 16384 + rv * 256);                       \
    }                                                                              \
  } while (0)

  // QK^T for 64-key subtile S_: stX[t][r] = S[k = kb + S_*64 + t*16 + lg*4+r][q]
#define QK_SUB(S_, STA, STB)                                                       \
  _Pragma("unroll")                                                                \
  for (int t = 0; t < 4; ++t) {                                                    \
    const int rbyte = ((S_) * 64 + t * 16 + l15) * 128;                            \
    bf16x8_t k0 = *reinterpret_cast<const bf16x8_t*>(Ksb + rbyte + ((16 * lg) ^ swz));       \
    bf16x8_t k1 = *reinterpret_cast<const bf16x8_t*>(Ksb + rbyte + ((64 + 16 * lg) ^ swz));  \
    f32x4_t s = {}; s = MFMA(k0, qA0, s); s = MFMA(k1, qA1, s); STA[t] = s;        \
    f32x4_t s2 = {}; s2 = MFMA(k0, qB0, s2); s2 = MFMA(k1, qB1, s2); STB[t] = s2;  \
  }

  // softmax + pack: ST[4] f32x4 logits -> PF[2] bf16x8; updates M, L, PO (defer-max)
#define SM_PACK(ST, MK, M_, L_, PO, PF, QG, CAUSAL, KB0)                           \
  do {                                                                             \
    float e[16]; float pmax = -3.0e38f;                                            \
    _Pragma("unroll")                                                              \
    for (int t = 0; t < 4; ++t)                                                    \
      _Pragma("unroll")                                                            \
      for (int r = 0; r < 4; ++r) {                                                \
        float v = fmaf(ST[t][r], SCL, MK[t][r]);                                   \
        if (CAUSAL) {                                                              \
          int k = (KB0) + t * 16 + lg * 4 + r;                                     \
          v = (k <= (QG)) ? v : EPS2;                                              \
        }                                                                          \
        e[t * 4 + r] = v; pmax = fmaxf(pmax, v);                                   \
      }                                                                            \
    pmax = fmaxf(pmax, __shfl_xor(pmax, 16));                                      \
    pmax = fmaxf(pmax, __shfl_xor(pmax, 32));                                      \
    if (!__all(pmax <= (M_) + 8.f)) {                                              \
      float mn = fmaxf(M_, pmax); float sc = exp2f((M_) - mn);                     \
      M_ = mn; L_ *= sc;                                                           \
      _Pragma("unroll") for (int f = 0; f < 4; ++f) PO[f] *= sc;                   \
    }                                                                              \
    float ps = 0.f;                                                                \
    _Pragma("unroll")                                                              \
    for (int i = 0; i < 16; ++i) { e[i] = exp2f(e[i] - (M_)); ps += e[i]; }        \
    ps += __shfl_xor(ps, 16); ps += __shfl_xor(ps, 32);                            \
    L_ += ps;                                                                      \
    _Pragma("unroll")                                                              \
    for (int g = 0; g < 2; ++g) {                                                  \
      union { uint32_t u[4]; bf16x8_t v; } pk_;                                    \
      _Pragma("unroll")                                                            \
      for (int j = 0; j < 4; ++j)                                                  \
        asm("v_cvt_pk_bf16_f32 %0, %1, %2"                                         \
            : "=v"(pk_.u[j]) : "v"(e[8 * g + 2 * j]), "v"(e[8 * g + 2 * j + 1]));  \
      PF[g] = pk_.v;                                                               \
    }                                                                              \
  } while (0)

  // PV for subtile S_: po += V^T x P (in-lane k-permutation matches SM_PACK order)
#define PV_SUB(S_, PFA, PFB)                                                       \
  _Pragma("unroll")                                                                \
  for (int g = 0; g < 2; ++g)                                                      \
    _Pragma("unroll")                                                              \
    for (int f = 0; f < 4; ++f) {                                                  \
      const int rbyte = (f * 16 + l15) * 256;                                      \
      const int cb = (S_) * 128 + 64 * g + 8 * lg;                                 \
      bf16x4_t va = *reinterpret_cast<const bf16x4_t*>(Vsb + rbyte + (cb ^ swz));          \
      bf16x4_t vb = *reinterpret_cast<const bf16x4_t*>(Vsb + rbyte + ((cb + 32) ^ swz));   \
      bf16x8_t vv = {va[0], va[1], va[2], va[3], vb[0], vb[1], vb[2], vb[3]};      \
      poA[f] = MFMA(vv, PFA[g], poA[f]);                                           \
      poB[f] = MFMA(vv, PFB[g], poB[f]);                                           \
    }

  int buf = 0;
  STAGE_PH(0, 0);

  // ---- full phases: no causal ops at all ----
  for (int ph = 0; ph < qst; ++ph) {
    const int kb = ph * 128;
    __syncthreads();                         // publishes phase ph; frees buf^1
    STAGE_PH(ph + 1, buf ^ 1);               // async; drains at next barrier
    const char* Ksb = smem + buf * 16384;
    const char* Vsb = smem + 32768 + buf * 16384;

    f32x4_t mk0[4], mk1[4];
#pragma unroll
    for (int t = 0; t < 4; ++t) {
      mk0[t] = *reinterpret_cast<const f32x4_t*>(&mp[kb + t * 16 + lg * 4]);
      mk1[t] = *reinterpret_cast<const f32x4_t*>(&mp[kb + 64 + t * 16 + lg * 4]);
    }

    f32x4_t stA0[4], stB0[4], stA1[4], stB1[4];
    __builtin_amdgcn_s_setprio(1);
    QK_SUB(0, stA0, stB0);
    QK_SUB(1, stA1, stB1);
    __builtin_amdgcn_s_setprio(0);

    bf16x8_t pfA[2], pfB[2];
    SM_PACK(stA0, mk0, mA, lA, poA, pfA, qg0, false, 0);
    SM_PACK(stB0, mk0, mB, lB, poB, pfB, qg1, false, 0);
    __builtin_amdgcn_s_setprio(1);
    PV_SUB(0, pfA, pfB);
    __builtin_amdgcn_s_setprio(0);
    SM_PACK(stA1, mk1, mA, lA, poA, pfA, qg0, false, 0);
    SM_PACK(stB1, mk1, mB, lB, poB, pfB, qg1, false, 0);
    __builtin_amdgcn_s_setprio(1);
    PV_SUB(1, pfA, pfB);
    __builtin_amdgcn_s_setprio(0);
    buf ^= 1;
  }

  // ---- diagonal phase (ph == qst): causal masking; sub1 only for waves 2,3 ----
  {
    const int kb = qst * 128;
    __syncthreads();
    const char* Ksb = smem + buf * 16384;
    const char* Vsb = smem + 32768 + buf * 16384;

    f32x4_t mk0[4], mk1[4];
#pragma unroll
    for (int t = 0; t < 4; ++t) {
      mk0[t] = *reinterpret_cast<const f32x4_t*>(&mp[kb + t * 16 + lg * 4]);
      mk1[t] = *reinterpret_cast<const f32x4_t*>(&mp[kb + 64 + t * 16 + lg * 4]);
    }

    f32x4_t stA0[4], stB0[4], stA1[4], stB1[4];
    bf16x8_t pfA[2], pfB[2];
    QK_SUB(0, stA0, stB0);
    SM_PACK(stA0, mk0, mA, lA, poA, pfA, qg0, true, kb);
    SM_PACK(stB0, mk0, mB, lB, poB, pfB, qg1, true, kb);
    PV_SUB(0, pfA, pfB);
    if (w >= 2) {                          // wave-uniform: sub1 exists only for w>=2
      QK_SUB(1, stA1, stB1);
      SM_PACK(stA1, mk1, mA, lA, poA, pfA, qg0, true, kb + 64);
      SM_PACK(stB1, mk1, mB, lB, poB, pfB, qg1, true, kb + 64);
      PV_SUB(1, pfA, pfB);
    }
  }
#undef STAGE_PH
#undef QK_SUB
#undef SM_PACK
#undef PV_SUB

  // ---- epilogue: normalize; all-masked rows -> uniform mean of V ----
  const float* vm = vmean + bh * DH;
  {
    const bool dead = (mA < -1.0e7f);
    const float inv = dead ? 0.f : 1.0f / lA;
    bf16_t* orow = ctxb + (size_t)(b * S_LEN + qg0) * DMODEL + h * DH;
#pragma unroll
    for (int f = 0; f < 4; ++f) {
      bf16x4_t o;
#pragma unroll
      for (int r = 0; r < 4; ++r) {
        int d = f * 16 + lg * 4 + r;
        o[r] = (bf16_t)(dead ? vm[d] : poA[f][r] * inv);
      }
      *reinterpret_cast<bf16x4_t*>(&orow[f * 16 + lg * 4]) = o;
    }
  }
  {
    const bool dead = (mB < -1.0e7f);
    const float inv = dead ? 0.f : 1.0f / lB;
    bf16_t* orow = ctxb + (size_t)(b * S_LEN + qg1) * DMODEL + h * DH;
#pragma unroll
    for (int f = 0; f < 4; ++f) {
      bf16x4_t o;
#pragma unroll
      for (int r = 0; r < 4; ++r) {
        int d = f * 16 + lg * 4 + r;
        o[r] = (bf16_t)(dead ? vm[d] : poB[f][r] * inv);
      }
      *reinterpret_cast<bf16x4_t*>(&orow[f * 16 + lg * 4]) = o;
    }
  }
}

extern "C" void kernel_launch(void* const* d_in, const int* in_sizes, int n_in,
                              void* d_out, int out_size, void* d_ws, size_t ws_size,
                              hipStream_t stream) {
  const float* x     = (const float*)d_in[0];
  const int*   amask = (const int*)d_in[1];
  const float* Wqkv  = (const float*)d_in[2];
  const float* bqkv  = (const float*)d_in[3];
  const float* Wproj = (const float*)d_in[4];
  const float* bproj = (const float*)d_in[5];
  float* out = (float*)d_out;

  char* ws = (char*)d_ws;
  bf16_t* xb    = (bf16_t*)(ws);                      // 8 MB  [4096][1024]
  bf16_t* WqT   = (bf16_t*)(ws + (8llu  << 20));      // 6 MB  [3072][1024]
  bf16_t* WpT   = (bf16_t*)(ws + (14llu << 20));      // 2 MB  [1024][1024]
  bf16_t* Qb    = (bf16_t*)(ws + (16llu << 20));      // 8 MB  [b,h,s,d]
  bf16_t* Kb    = (bf16_t*)(ws + (24llu << 20));      // 8 MB  [b,h,s,d]
  bf16_t* Vt    = (bf16_t*)(ws + (32llu << 20));      // 8 MB  [b,h,d,s]
  bf16_t* ctxb  = (bf16_t*)(ws + (40llu << 20));      // 8 MB  [4096][1024]
  float*  vmean = (float*) (ws + (48llu << 20));      // 8 KB  [32][64]
  float*  mskf  = (float*) (ws + (48llu << 20) + 65536);  // 16 KB [2][2048]

  k_cvt_bf16<<<4096, 256, 0, stream>>>(x, xb, (2 * S_LEN * DMODEL) / 4);
  k_mask<<<16, 256, 0, stream>>>(amask, mskf, 2 * S_LEN);
  k_transpose_bf16<<<dim3(3072 / 32, 1024 / 32), dim3(32, 8), 0, stream>>>(Wqkv, WqT, 1024, 3072);
  k_transpose_bf16<<<dim3(1024 / 32, 1024 / 32), dim3(32, 8), 0, stream>>>(Wproj, WpT, 1024, 1024);
  k_gemm<0><<<dim3(3072 / 128, 4096 / 128), 256, 0, stream>>>(
      xb, WqT, bqkv, Qb, Kb, Vt, nullptr, 4096, 3072, 1024);
  k_vmean<<<32, 256, 0, stream>>>(Vt, vmean);
  k_attn<<<dim3(32, 16), 256, 0, stream>>>(Qb, Kb, Vt, mskf, vmean, ctxb);
  k_gemm<1><<<dim3(1024 / 128, 4096 / 128), 256, 0, stream>>>(
      ctxb, WpT, bproj, nullptr, nullptr, nullptr, out, 4096, 1024, 1024);
}